// Round 2
// baseline (261.054 us; speedup 1.0000x reference)
//
#include <hip/hip_runtime.h>
#include <hip/hip_bf16.h>
#include <stdint.h>

// Problem constants
#define B_SZ 2
#define T_SZ 2048
#define C_SZ 1024
#define H_SZ 16
#define HD   64
#define BH   (B_SZ * H_SZ)   // 32
#define M_SZ (B_SZ * T_SZ)   // 4096
#define N_QKV (3 * C_SZ)     // 3072

typedef __attribute__((ext_vector_type(8))) __bf16 bf16x8;
typedef __attribute__((ext_vector_type(4))) float f32x4;
typedef __attribute__((ext_vector_type(8))) unsigned short us8;
typedef __attribute__((ext_vector_type(4))) unsigned short us4;

__device__ __forceinline__ unsigned short f2bf(float f) {
    unsigned int u = __builtin_bit_cast(unsigned int, f);
    u += 0x7fffu + ((u >> 16) & 1u);   // round-to-nearest-even
    return (unsigned short)(u >> 16);
}

// ---------------- transpose: f32 [K][N] -> bf16 [N][K] ----------------
__global__ __launch_bounds__(256) void k_transpose(const float* __restrict__ in,
                                                   unsigned short* __restrict__ out,
                                                   int K, int N) {
    __shared__ float tile[32][33];
    const int n0 = blockIdx.x * 32, k0 = blockIdx.y * 32;
    const int tx = threadIdx.x, ty = threadIdx.y;  // (32, 8)
    #pragma unroll
    for (int j = 0; j < 32; j += 8)
        tile[ty + j][tx] = in[(size_t)(k0 + ty + j) * N + (n0 + tx)];
    __syncthreads();
    #pragma unroll
    for (int j = 0; j < 32; j += 8)
        out[(size_t)(n0 + ty + j) * K + (k0 + tx)] = f2bf(tile[tx][ty + j]);
}

// ---------------- GEMM: C[M,N] = A[M,K] @ Bt[N,K]^T + bias ----------------
// AMODE 0: A is f32 (x). AMODE 1: A is bf16 (y).
// EPI 0: f32 out row-major + bias. EPI 1: scatter bf16 into Q/K/V [BH][T][HD].
// LDS rows are 64 bf16 = 128B, XOR-swizzled: byteInRow ^= (row&7)<<4.
template <int AMODE, int EPI>
__global__ __launch_bounds__(256) void k_gemm(const void* __restrict__ Aptr,
                                              const unsigned short* __restrict__ Bt,
                                              const float* __restrict__ bias,
                                              float* __restrict__ Cout,
                                              unsigned short* __restrict__ q_ws,
                                              unsigned short* __restrict__ k_ws,
                                              unsigned short* __restrict__ v_ws,
                                              int M, int N, int K) {
    __shared__ __attribute__((aligned(16))) unsigned short Ald[128 * 64];
    __shared__ __attribute__((aligned(16))) unsigned short Bld[128 * 64];
    const int tid = threadIdx.x;
    const int wid = tid >> 6, lane = tid & 63;
    const int wr = wid >> 1, wc = wid & 1;
    const int g = lane >> 4, l15 = lane & 15;
    const int m0 = blockIdx.y * 128, n0 = blockIdx.x * 128;

    f32x4 acc[4][4];
    #pragma unroll
    for (int i = 0; i < 4; ++i)
        #pragma unroll
        for (int j = 0; j < 4; ++j) acc[i][j] = (f32x4){0.f, 0.f, 0.f, 0.f};

    for (int k0 = 0; k0 < K; k0 += 64) {
        __syncthreads();
        if (AMODE == 0) {
            const float* A = (const float*)Aptr;
            #pragma unroll
            for (int i = 0; i < 8; ++i) {
                int c = tid + 256 * i;                 // 2048 float4 chunks
                int row = c >> 4, q4 = (c & 15) << 2;  // q4: f32 col in tile
                f32x4 v = *(const f32x4*)(A + (size_t)(m0 + row) * K + (k0 + q4));
                us4 hh;
                #pragma unroll
                for (int j = 0; j < 4; ++j) hh[j] = f2bf(v[j]);
                int byt = row * 128 + ((q4 * 2) ^ ((row & 7) << 4));
                *(us4*)((char*)Ald + byt) = hh;
            }
        } else {
            const unsigned short* A = (const unsigned short*)Aptr;
            #pragma unroll
            for (int i = 0; i < 4; ++i) {
                int c = tid + 256 * i;                 // 1024 16B chunks
                int row = c >> 3, s8 = (c & 7) << 3;
                us8 v = *(const us8*)(A + (size_t)(m0 + row) * K + (k0 + s8));
                int byt = row * 128 + ((s8 * 2) ^ ((row & 7) << 4));
                *(us8*)((char*)Ald + byt) = v;
            }
        }
        #pragma unroll
        for (int i = 0; i < 4; ++i) {
            int c = tid + 256 * i;
            int row = c >> 3, s8 = (c & 7) << 3;
            us8 v = *(const us8*)(Bt + (size_t)(n0 + row) * K + (k0 + s8));
            int byt = row * 128 + ((s8 * 2) ^ ((row & 7) << 4));
            *(us8*)((char*)Bld + byt) = v;
        }
        __syncthreads();

        #pragma unroll
        for (int ks = 0; ks < 2; ++ks) {
            bf16x8 af[4], bfr[4];
            #pragma unroll
            for (int mi = 0; mi < 4; ++mi) {
                int row = wr * 64 + mi * 16 + l15;
                int byt = row * 128 + (((ks * 64) + (g * 16)) ^ ((row & 7) << 4));
                af[mi] = *(const bf16x8*)((const char*)Ald + byt);
            }
            #pragma unroll
            for (int nj = 0; nj < 4; ++nj) {
                int row = wc * 64 + nj * 16 + l15;
                int byt = row * 128 + (((ks * 64) + (g * 16)) ^ ((row & 7) << 4));
                bfr[nj] = *(const bf16x8*)((const char*)Bld + byt);
            }
            #pragma unroll
            for (int mi = 0; mi < 4; ++mi)
                #pragma unroll
                for (int nj = 0; nj < 4; ++nj)
                    acc[mi][nj] = __builtin_amdgcn_mfma_f32_16x16x32_bf16(
                        af[mi], bfr[nj], acc[mi][nj], 0, 0, 0);
        }
    }

    if (EPI == 0) {
        #pragma unroll
        for (int nj = 0; nj < 4; ++nj) {
            int col = n0 + wc * 64 + nj * 16 + l15;
            float bv = bias[col];
            #pragma unroll
            for (int mi = 0; mi < 4; ++mi) {
                int rowb = m0 + wr * 64 + mi * 16 + g * 4;
                #pragma unroll
                for (int r = 0; r < 4; ++r)
                    Cout[(size_t)(rowb + r) * N + col] = acc[mi][nj][r] + bv;
            }
        }
    } else {
        #pragma unroll
        for (int nj = 0; nj < 4; ++nj) {
            int col = n0 + wc * 64 + nj * 16 + l15;   // 0..3071
            float bv = bias[col];
            int which = col >> 10;
            int c10 = col & 1023;
            int h = c10 >> 6, d = c10 & 63;
            unsigned short* base = (which == 0) ? q_ws : (which == 1) ? k_ws : v_ws;
            #pragma unroll
            for (int mi = 0; mi < 4; ++mi) {
                #pragma unroll
                for (int r = 0; r < 4; ++r) {
                    int row = m0 + wr * 64 + mi * 16 + g * 4 + r;  // 0..4095
                    int bb = row >> 11, t = row & 2047;
                    base[((size_t)(bb * H_SZ + h) * T_SZ + t) * HD + d] =
                        f2bf(acc[mi][nj][r] + bv);
                }
            }
        }
    }
}

// ---------------- causal flash attention ----------------
// grid (qblocks=32, bh=32); 256 threads = 4 waves, wave w owns q rows qb*64+w*16..+15.
__global__ __launch_bounds__(256) void k_attn(const unsigned short* __restrict__ q_ws,
                                              const unsigned short* __restrict__ k_ws,
                                              const unsigned short* __restrict__ v_ws,
                                              unsigned short* __restrict__ y_ws) {
    __shared__ __attribute__((aligned(16))) unsigned short Kld[64 * 64];
    __shared__ __attribute__((aligned(16))) unsigned short Vtld[64 * 64];  // [d][k]
    __shared__ __attribute__((aligned(16))) unsigned short Pld[4 * 16 * 64];
    const int tid = threadIdx.x;
    const int wid = tid >> 6, lane = tid & 63;
    const int g = lane >> 4, l15 = lane & 15;
    const int qb = blockIdx.x, bh = blockIdx.y;
    const size_t bh_off = (size_t)bh * T_SZ * HD;

    // Q fragments held in registers (A operand, rows = wave's 16 q rows)
    const int qrow = qb * 64 + wid * 16 + l15;
    bf16x8 aq[2];
    aq[0] = *(const bf16x8*)(q_ws + bh_off + (size_t)qrow * HD + g * 8);
    aq[1] = *(const bf16x8*)(q_ws + bh_off + (size_t)qrow * HD + 32 + g * 8);

    float m_run[4], l_run[4];
    f32x4 acc[4];
    #pragma unroll
    for (int r = 0; r < 4; ++r) { m_run[r] = -1e30f; l_run[r] = 0.f; }
    #pragma unroll
    for (int dt = 0; dt < 4; ++dt) acc[dt] = (f32x4){0.f, 0.f, 0.f, 0.f};

    char* Pw = (char*)Pld + wid * 2048;  // wave-private 16x64 bf16 tile

    for (int kv = 0; kv <= qb; ++kv) {
        __syncthreads();
        {   // stage K [64][64] (swizzled) and V transposed -> Vt [d][k]
            const unsigned short* Ksrc = k_ws + bh_off + (size_t)kv * 64 * HD;
            #pragma unroll
            for (int i = 0; i < 2; ++i) {
                int c = tid + 256 * i;
                int row = c >> 3, s8 = (c & 7) << 3;
                us8 v = *(const us8*)(Ksrc + row * HD + s8);
                *(us8*)((char*)Kld + row * 128 + ((s8 * 2) ^ ((row & 7) << 4))) = v;
            }
            const unsigned short* Vsrc = v_ws + bh_off + (size_t)kv * 64 * HD;
            #pragma unroll
            for (int i = 0; i < 2; ++i) {
                int c = tid + 256 * i;
                int kr = c & 63, d8 = (c >> 6) << 3;
                us8 v = *(const us8*)(Vsrc + kr * HD + d8);
                #pragma unroll
                for (int j = 0; j < 8; ++j) {
                    int row = d8 + j;
                    *(unsigned short*)((char*)Vtld + row * 128 +
                                       ((kr * 2) ^ ((row & 7) << 4))) = v[j];
                }
            }
        }
        __syncthreads();

        // S = Q @ K^T  (per wave: 16 q x 64 keys)
        f32x4 s[4];
        #pragma unroll
        for (int kt = 0; kt < 4; ++kt) {
            f32x4 sv = (f32x4){0.f, 0.f, 0.f, 0.f};
            #pragma unroll
            for (int ks = 0; ks < 2; ++ks) {
                int row = kt * 16 + l15;
                bf16x8 bk = *(const bf16x8*)((const char*)Kld + row * 128 +
                                             (((ks * 64) + (g * 16)) ^ ((row & 7) << 4)));
                sv = __builtin_amdgcn_mfma_f32_16x16x32_bf16(aq[ks], bk, sv, 0, 0, 0);
            }
            #pragma unroll
            for (int r = 0; r < 4; ++r) sv[r] *= 0.125f;  // 1/sqrt(64)
            s[kt] = sv;
        }

        if (kv == qb) {  // diagonal tile: causal mask (key > q -> -inf)
            #pragma unroll
            for (int kt = 0; kt < 4; ++kt) {
                int key = kt * 16 + l15;
                int qloc = wid * 16 + g * 4;
                #pragma unroll
                for (int r = 0; r < 4; ++r)
                    if (key > qloc + r) s[kt][r] = -1e30f;
            }
        }

        // online softmax (row r lives in the 16 lanes sharing g; reduce over l15)
        float alpha[4];
        #pragma unroll
        for (int r = 0; r < 4; ++r) {
            float mx = fmaxf(fmaxf(s[0][r], s[1][r]), fmaxf(s[2][r], s[3][r]));
            mx = fmaxf(mx, __shfl_xor(mx, 1, 64));
            mx = fmaxf(mx, __shfl_xor(mx, 2, 64));
            mx = fmaxf(mx, __shfl_xor(mx, 4, 64));
            mx = fmaxf(mx, __shfl_xor(mx, 8, 64));
            float mnew = fmaxf(m_run[r], mx);
            alpha[r] = exp2f((m_run[r] - mnew) * 1.44269504f);
            m_run[r] = mnew;
        }
        float rs[4] = {0.f, 0.f, 0.f, 0.f};
        #pragma unroll
        for (int kt = 0; kt < 4; ++kt) {
            #pragma unroll
            for (int r = 0; r < 4; ++r) {
                float p = exp2f((s[kt][r] - m_run[r]) * 1.44269504f);
                s[kt][r] = p;
                rs[r] += p;
            }
        }
        #pragma unroll
        for (int r = 0; r < 4; ++r) {
            float t = rs[r];
            t += __shfl_xor(t, 1, 64);
            t += __shfl_xor(t, 2, 64);
            t += __shfl_xor(t, 4, 64);
            t += __shfl_xor(t, 8, 64);
            l_run[r] = l_run[r] * alpha[r] + t;
        }
        #pragma unroll
        for (int dt = 0; dt < 4; ++dt)
            #pragma unroll
            for (int r = 0; r < 4; ++r) acc[dt][r] *= alpha[r];

        // P (D-layout) -> wave-private LDS -> reload as A-fragments
        #pragma unroll
        for (int kt = 0; kt < 4; ++kt) {
            #pragma unroll
            for (int r = 0; r < 4; ++r) {
                int row = g * 4 + r;
                int byt = row * 128 + (((kt * 16 + l15) * 2) ^ ((row & 7) << 4));
                *(unsigned short*)(Pw + byt) = f2bf(s[kt][r]);
            }
        }
        bf16x8 ap[2];
        #pragma unroll
        for (int ks = 0; ks < 2; ++ks) {
            int row = l15;
            ap[ks] = *(const bf16x8*)((const char*)Pw + row * 128 +
                                      (((ks * 64) + (g * 16)) ^ ((row & 7) << 4)));
        }
        #pragma unroll
        for (int dt = 0; dt < 4; ++dt) {
            #pragma unroll
            for (int ks = 0; ks < 2; ++ks) {
                int row = dt * 16 + l15;
                bf16x8 bv = *(const bf16x8*)((const char*)Vtld + row * 128 +
                                             (((ks * 64) + (g * 16)) ^ ((row & 7) << 4)));
                acc[dt] = __builtin_amdgcn_mfma_f32_16x16x32_bf16(ap[ks], bv, acc[dt], 0, 0, 0);
            }
        }
    }

    // epilogue: y[b, t, h*64 + d] = acc / l
    const int b = bh >> 4, h = bh & 15;
    #pragma unroll
    for (int r = 0; r < 4; ++r) {
        int t = qb * 64 + wid * 16 + g * 4 + r;
        float inv = 1.0f / l_run[r];
        #pragma unroll
        for (int dt = 0; dt < 4; ++dt)
            y_ws[((size_t)(b * T_SZ + t)) * C_SZ + h * 64 + dt * 16 + l15] =
                f2bf(acc[dt][r] * inv);
    }
}

// ---------------- launcher ----------------
extern "C" void kernel_launch(void* const* d_in, const int* in_sizes, int n_in,
                              void* d_out, int out_size, void* d_ws, size_t ws_size,
                              hipStream_t stream) {
    const float* x      = (const float*)d_in[0];
    const float* w_attn = (const float*)d_in[1];
    const float* b_attn = (const float*)d_in[2];
    const float* w_proj = (const float*)d_in[3];
    const float* b_proj = (const float*)d_in[4];
    float* out = (float*)d_out;

    // workspace layout (bytes), total ~40 MB
    char* ws = (char*)d_ws;
    unsigned short* q_ws = (unsigned short*)(ws + 0);          // 8 MB  [BH][T][HD] bf16
    unsigned short* k_ws = (unsigned short*)(ws + 8388608);    // 8 MB
    unsigned short* v_ws = (unsigned short*)(ws + 16777216);   // 8 MB
    unsigned short* y_ws = (unsigned short*)(ws + 25165824);   // 8 MB  [B][T][C] bf16
    unsigned short* wta  = (unsigned short*)(ws + 33554432);   // 6 MB  [3C][C] bf16
    unsigned short* wtp  = (unsigned short*)(ws + 39845888);   // 2 MB  [C][C] bf16

    // 1) weight transposes f32 [K][N] -> bf16 [N][K]
    k_transpose<<<dim3(N_QKV / 32, C_SZ / 32), dim3(32, 8), 0, stream>>>(
        w_attn, wta, C_SZ, N_QKV);
    k_transpose<<<dim3(C_SZ / 32, C_SZ / 32), dim3(32, 8), 0, stream>>>(
        w_proj, wtp, C_SZ, C_SZ);

    // 2) QKV GEMM: x[4096,1024] @ w_attn -> Q/K/V bf16 [BH][T][HD]
    k_gemm<0, 1><<<dim3(N_QKV / 128, M_SZ / 128), 256, 0, stream>>>(
        x, wta, b_attn, nullptr, q_ws, k_ws, v_ws, M_SZ, N_QKV, C_SZ);

    // 3) causal flash attention -> y bf16 [B][T][C]
    k_attn<<<dim3(T_SZ / 64, BH), 256, 0, stream>>>(q_ws, k_ws, v_ws, y_ws);

    // 4) proj GEMM: y[4096,1024] @ w_proj + b_proj -> f32 out
    k_gemm<1, 0><<<dim3(C_SZ / 128, M_SZ / 128), 256, 0, stream>>>(
        y_ws, wtp, b_proj, out, nullptr, nullptr, nullptr, M_SZ, C_SZ, C_SZ);
}

// Round 3
// 143.117 us; speedup vs baseline: 1.8241x; 1.8241x over previous
//
#include <hip/hip_runtime.h>
#include <hip/hip_bf16.h>
#include <stdint.h>

// Problem constants
#define B_SZ 2
#define T_SZ 2048
#define C_SZ 1024
#define H_SZ 16
#define HD   64
#define BH   (B_SZ * H_SZ)   // 32
#define M_SZ (B_SZ * T_SZ)   // 4096
#define N_QKV (3 * C_SZ)     // 3072

typedef __attribute__((ext_vector_type(8))) __bf16 bf16x8;
typedef __attribute__((ext_vector_type(4))) float f32x4;
typedef __attribute__((ext_vector_type(8))) unsigned short us8;
typedef __attribute__((ext_vector_type(4))) unsigned short us4;
typedef __attribute__((ext_vector_type(4))) unsigned int u32x4;

__device__ __forceinline__ unsigned short f2bf(float f) {
    unsigned int u = __builtin_bit_cast(unsigned int, f);
    u += 0x7fffu + ((u >> 16) & 1u);   // round-to-nearest-even
    return (unsigned short)(u >> 16);
}

// async global->LDS, 16B per lane; lds base must be wave-uniform (HW adds lane*16)
__device__ __forceinline__ void gll16(const unsigned short* g, unsigned short* l) {
    __builtin_amdgcn_global_load_lds(
        (const __attribute__((address_space(1))) unsigned int*)g,
        (__attribute__((address_space(3))) unsigned int*)l, 16, 0, 0);
}

// ---------------- transpose: f32 [K][N] -> bf16 [N][K] ----------------
__global__ __launch_bounds__(256) void k_transpose(const float* __restrict__ in,
                                                   unsigned short* __restrict__ out,
                                                   int K, int N) {
    __shared__ float tile[32][33];
    const int n0 = blockIdx.x * 32, k0 = blockIdx.y * 32;
    const int tx = threadIdx.x, ty = threadIdx.y;  // (32, 8)
    #pragma unroll
    for (int j = 0; j < 32; j += 8)
        tile[ty + j][tx] = in[(size_t)(k0 + ty + j) * N + (n0 + tx)];
    __syncthreads();
    #pragma unroll
    for (int j = 0; j < 32; j += 8)
        out[(size_t)(n0 + ty + j) * K + (k0 + tx)] = f2bf(tile[tx][ty + j]);
}

// ---------------- convert: f32 -> bf16, 8 elems/thread ----------------
__global__ __launch_bounds__(256) void k_cvt(const float* __restrict__ in,
                                             unsigned short* __restrict__ out) {
    const size_t i = ((size_t)blockIdx.x * 256 + threadIdx.x) * 8;
    f32x4 a = *(const f32x4*)(in + i);
    f32x4 b = *(const f32x4*)(in + i + 4);
    us8 o;
    #pragma unroll
    for (int j = 0; j < 4; ++j) { o[j] = f2bf(a[j]); o[4 + j] = f2bf(b[j]); }
    *(us8*)(out + i) = o;
}

// ---------------- GEMM: C[M,N] = A[M,K](bf16) @ Bt[N,K]^T + bias ----------------
// EPI 0: f32 out row-major + bias. EPI 1: scatter bf16 into Q/K (row-major) and V^T.
// LDS tiles 128 rows x 128B; XOR-swizzle byteInRow ^= (row&7)<<4, applied on the
// pre-swizzled GLOBAL source address (gll dest is linear) and on the read side.
template <int EPI>
__global__ __launch_bounds__(256) void k_gemm(const unsigned short* __restrict__ A,
                                              const unsigned short* __restrict__ Bt,
                                              const float* __restrict__ bias,
                                              float* __restrict__ Cout,
                                              unsigned short* __restrict__ q_ws,
                                              unsigned short* __restrict__ k_ws,
                                              unsigned short* __restrict__ vT_ws,
                                              int M, int N, int K) {
    __shared__ __attribute__((aligned(16))) unsigned short Ald[128 * 64];
    __shared__ __attribute__((aligned(16))) unsigned short Bld[128 * 64];
    const int tid = threadIdx.x;
    const int wid = tid >> 6, lane = tid & 63;
    const int wr = wid >> 1, wc = wid & 1;
    const int g = lane >> 4, l15 = lane & 15;
    const int m0 = blockIdx.y * 128, n0 = blockIdx.x * 128;

    f32x4 acc[4][4];
    #pragma unroll
    for (int i = 0; i < 4; ++i)
        #pragma unroll
        for (int j = 0; j < 4; ++j) acc[i][j] = (f32x4){0.f, 0.f, 0.f, 0.f};

    for (int k0 = 0; k0 < K; k0 += 64) {
        __syncthreads();
        #pragma unroll
        for (int i = 0; i < 4; ++i) {
            int c = i * 256 + tid;
            int row = c >> 3;
            int colb = ((c & 7) << 4) ^ ((row & 7) << 4);   // pre-swizzled source col
            gll16(A  + (size_t)(m0 + row) * K + k0 + (colb >> 1), Ald + i * 2048 + wid * 512);
            gll16(Bt + (size_t)(n0 + row) * K + k0 + (colb >> 1), Bld + i * 2048 + wid * 512);
        }
        __syncthreads();

        #pragma unroll
        for (int ks = 0; ks < 2; ++ks) {
            bf16x8 af[4], bfr[4];
            #pragma unroll
            for (int mi = 0; mi < 4; ++mi) {
                int row = wr * 64 + mi * 16 + l15;
                af[mi] = *(const bf16x8*)((const char*)Ald + row * 128 +
                                          ((ks * 64 + g * 16) ^ ((row & 7) << 4)));
            }
            #pragma unroll
            for (int nj = 0; nj < 4; ++nj) {
                int row = wc * 64 + nj * 16 + l15;
                bfr[nj] = *(const bf16x8*)((const char*)Bld + row * 128 +
                                           ((ks * 64 + g * 16) ^ ((row & 7) << 4)));
            }
            #pragma unroll
            for (int mi = 0; mi < 4; ++mi)
                #pragma unroll
                for (int nj = 0; nj < 4; ++nj)
                    acc[mi][nj] = __builtin_amdgcn_mfma_f32_16x16x32_bf16(
                        af[mi], bfr[nj], acc[mi][nj], 0, 0, 0);
        }
    }

    if (EPI == 0) {
        #pragma unroll
        for (int nj = 0; nj < 4; ++nj) {
            int col = n0 + wc * 64 + nj * 16 + l15;
            float bv = bias[col];
            #pragma unroll
            for (int mi = 0; mi < 4; ++mi) {
                int rowb = m0 + wr * 64 + mi * 16 + g * 4;
                #pragma unroll
                for (int r = 0; r < 4; ++r)
                    Cout[(size_t)(rowb + r) * N + col] = acc[mi][nj][r] + bv;
            }
        }
    } else {
        #pragma unroll
        for (int nj = 0; nj < 4; ++nj) {
            int col = n0 + wc * 64 + nj * 16 + l15;   // 0..3071
            float bv = bias[col];
            int which = col >> 10;
            int c10 = col & 1023;
            int h = c10 >> 6, d = c10 & 63;
            #pragma unroll
            for (int mi = 0; mi < 4; ++mi) {
                #pragma unroll
                for (int r = 0; r < 4; ++r) {
                    int row = m0 + wr * 64 + mi * 16 + g * 4 + r;  // 0..4095
                    int bb = row >> 11, t = row & 2047;
                    unsigned short val = f2bf(acc[mi][nj][r] + bv);
                    if (which == 2)
                        vT_ws[((size_t)(bb * H_SZ + h) * HD + d) * T_SZ + t] = val;       // V^T
                    else
                        (which ? k_ws : q_ws)[((size_t)(bb * H_SZ + h) * T_SZ + t) * HD + d] = val;
                }
            }
        }
    }
}

// ---------------- causal flash attention ----------------
// 1D grid of 1024; bh = n>>5, qb = ((n&31)+bh)&31 (per-CU work balance).
// 256 threads = 4 waves, wave w owns q rows qb*64 + w*16 .. +15.
// S^T = mfma(K,Q) so softmax rows are lane-local; P rebuilt in-register via
// cvt_pk + permlane32/16_swap (no P LDS round trip). K/V double-buffered via
// global_load_lds with pre-swizzled source, one barrier per KV step.
__global__ __launch_bounds__(256) void k_attn(const unsigned short* __restrict__ q_ws,
                                              const unsigned short* __restrict__ k_ws,
                                              const unsigned short* __restrict__ vT_ws,
                                              unsigned short* __restrict__ y_ws) {
    __shared__ __attribute__((aligned(16))) unsigned short Kbuf[2][4096];
    __shared__ __attribute__((aligned(16))) unsigned short Vbuf[2][4096];
    const int tid = threadIdx.x;
    const int wid = tid >> 6, lane = tid & 63;
    const int g = lane >> 4, l15 = lane & 15;
    const int n = blockIdx.x;
    const int bh = n >> 5;
    const int qb = ((n & 31) + bh) & 31;
    const size_t kv_off = (size_t)bh * T_SZ * HD;

    // Q fragments (rows = wave's 16 q rows); also valid as B-operand of mfma(K,Q)
    const int qrow = qb * 64 + wid * 16 + l15;
    bf16x8 aq[2];
    aq[0] = *(const bf16x8*)(q_ws + kv_off + (size_t)qrow * HD + g * 8);
    aq[1] = *(const bf16x8*)(q_ws + kv_off + (size_t)qrow * HD + 32 + g * 8);

    float m_run = -3e38f, l_run = 0.f;
    f32x4 acc[4];
    #pragma unroll
    for (int dt = 0; dt < 4; ++dt) acc[dt] = (f32x4){0.f, 0.f, 0.f, 0.f};

    const unsigned short* Kg = k_ws + kv_off;
    const unsigned short* Vg = vT_ws + (size_t)bh * HD * T_SZ;

    auto stageK = [&](int kv, int buf) {
        #pragma unroll
        for (int i = 0; i < 2; ++i) {
            int c = i * 256 + tid;
            int row = c >> 3;
            int colb = ((c & 7) << 4) ^ ((row & 7) << 4);
            gll16(Kg + (size_t)(kv * 64 + row) * HD + (colb >> 1),
                  &Kbuf[buf][i * 2048 + wid * 512]);
        }
    };
    auto stageV = [&](int kv, int buf) {
        #pragma unroll
        for (int i = 0; i < 2; ++i) {
            int c = i * 256 + tid;
            int row = c >> 3;                             // d index
            int colb = ((c & 7) << 4) ^ ((row & 7) << 4); // t-offset bytes in tile
            gll16(Vg + (size_t)row * T_SZ + kv * 64 + (colb >> 1),
                  &Vbuf[buf][i * 2048 + wid * 512]);
        }
    };

    stageK(0, 0); stageV(0, 0);
    int cur = 0;
    const int qloc = wid * 16 + l15;
    const float SC = 0.125f * 1.44269504f;  // 1/sqrt(64) * log2(e)

    for (int kv = 0; kv <= qb; ++kv) {
        __syncthreads();   // drains prefetch vmcnt; buf[cur] ready, buf[cur^1] free
        if (kv < qb) { stageK(kv + 1, cur ^ 1); stageV(kv + 1, cur ^ 1); }
        const char* Kb = (const char*)Kbuf[cur];
        const char* Vb = (const char*)Vbuf[cur];

        // S^T = K @ Q^T : D[row=key][col=q]; lane holds keys kt*16+4g+r for q=l15
        f32x4 st[4];
        #pragma unroll
        for (int kt = 0; kt < 4; ++kt) {
            f32x4 sv = (f32x4){0.f, 0.f, 0.f, 0.f};
            #pragma unroll
            for (int ks = 0; ks < 2; ++ks) {
                int row = kt * 16 + l15;
                bf16x8 ak = *(const bf16x8*)(Kb + row * 128 +
                                             ((ks * 64 + g * 16) ^ ((row & 7) << 4)));
                sv = __builtin_amdgcn_mfma_f32_16x16x32_bf16(ak, aq[ks], sv, 0, 0, 0);
            }
            st[kt] = sv;
        }

        // scale into log2 domain + causal mask (key > q -> -big)
        float t[16];
        #pragma unroll
        for (int kt = 0; kt < 4; ++kt)
            #pragma unroll
            for (int r = 0; r < 4; ++r) {
                float v = st[kt][r] * SC;
                if (kv == qb && (kt * 16 + g * 4 + r) > qloc) v = -3e38f;
                t[kt * 4 + r] = v;
            }

        // online softmax: 15 in-lane fmax + 2 shfl (all 16 keys-per-lane, q=l15)
        float mx = t[0];
        #pragma unroll
        for (int i = 1; i < 16; ++i) mx = fmaxf(mx, t[i]);
        mx = fmaxf(mx, __shfl_xor(mx, 16, 64));
        mx = fmaxf(mx, __shfl_xor(mx, 32, 64));
        float mnew = fmaxf(m_run, mx);
        float alpha = exp2f(m_run - mnew);
        m_run = mnew;

        float p[16], sum = 0.f;
        #pragma unroll
        for (int i = 0; i < 16; ++i) { p[i] = exp2f(t[i] - mnew); sum += p[i]; }
        sum += __shfl_xor(sum, 16, 64);
        sum += __shfl_xor(sum, 32, 64);
        l_run = l_run * alpha + sum;

        // alpha (indexed by q=l15) -> O layout (q = 4g+r): 4 bpermutes
        float ao[4];
        #pragma unroll
        for (int r = 0; r < 4; ++r) {
            int ai = __builtin_amdgcn_ds_bpermute((g * 4 + r) * 4,
                                                  __builtin_bit_cast(int, alpha));
            ao[r] = __builtin_bit_cast(float, ai);
        }
        #pragma unroll
        for (int dt = 0; dt < 4; ++dt)
            #pragma unroll
            for (int r = 0; r < 4; ++r) acc[dt][r] *= ao[r];

        // P -> bf16 pairs, then permlane swaps rebuild the A-fragment in-register
        unsigned int pk0[4], pk1[4];
        #pragma unroll
        for (int kt = 0; kt < 4; ++kt) {
            asm("v_cvt_pk_bf16_f32 %0, %1, %2" : "=v"(pk0[kt]) : "v"(p[kt * 4 + 0]), "v"(p[kt * 4 + 1]));
            asm("v_cvt_pk_bf16_f32 %0, %1, %2" : "=v"(pk1[kt]) : "v"(p[kt * 4 + 2]), "v"(p[kt * 4 + 3]));
        }
        #pragma unroll
        for (int ks = 0; ks < 2; ++ks) {
            unsigned int x0 = pk0[2 * ks], y0 = pk0[2 * ks + 1];
            unsigned int x1 = pk1[2 * ks], y1 = pk1[2 * ks + 1];
            // after: x = {X.Q0, X.Q2, Y.Q0, Y.Q2}, y = {X.Q1, X.Q3, Y.Q1, Y.Q3}
            asm("v_permlane32_swap_b32 %0, %1" : "+v"(x0), "+v"(y0));
            asm("v_permlane16_swap_b32 %0, %1" : "+v"(x0), "+v"(y0));
            asm("v_permlane32_swap_b32 %0, %1" : "+v"(x1), "+v"(y1));
            asm("v_permlane16_swap_b32 %0, %1" : "+v"(x1), "+v"(y1));
            bf16x8 ap = __builtin_bit_cast(bf16x8, (u32x4){x0, x1, y0, y1});
            #pragma unroll
            for (int dt = 0; dt < 4; ++dt) {
                int row = dt * 16 + l15;
                bf16x8 bv = *(const bf16x8*)(Vb + row * 128 +
                                             ((ks * 64 + g * 16) ^ ((row & 7) << 4)));
                acc[dt] = __builtin_amdgcn_mfma_f32_16x16x32_bf16(ap, bv, acc[dt], 0, 0, 0);
            }
        }
        cur ^= 1;
    }

    // epilogue: gather l for q=4g+r, normalize, store y[b,t,h*64+d]
    float lo[4];
    #pragma unroll
    for (int r = 0; r < 4; ++r) {
        int li = __builtin_amdgcn_ds_bpermute((g * 4 + r) * 4,
                                              __builtin_bit_cast(int, l_run));
        lo[r] = __builtin_bit_cast(float, li);
    }
    const int b = bh >> 4, h = bh & 15;
    #pragma unroll
    for (int r = 0; r < 4; ++r) {
        int tq = qb * 64 + wid * 16 + g * 4 + r;
        float inv = 1.0f / lo[r];
        #pragma unroll
        for (int dt = 0; dt < 4; ++dt)
            y_ws[(size_t)(b * T_SZ + tq) * C_SZ + h * 64 + dt * 16 + l15] =
                f2bf(acc[dt][r] * inv);
    }
}

// ---------------- launcher ----------------
extern "C" void kernel_launch(void* const* d_in, const int* in_sizes, int n_in,
                              void* d_out, int out_size, void* d_ws, size_t ws_size,
                              hipStream_t stream) {
    const float* x      = (const float*)d_in[0];
    const float* w_attn = (const float*)d_in[1];
    const float* b_attn = (const float*)d_in[2];
    const float* w_proj = (const float*)d_in[3];
    const float* b_proj = (const float*)d_in[4];
    float* out = (float*)d_out;

    // workspace layout (bytes), total 40 MB
    char* ws = (char*)d_ws;
    unsigned short* q_ws  = (unsigned short*)(ws + 0);         // 8 MB [BH][T][HD]
    unsigned short* k_ws  = (unsigned short*)(ws + 8388608);   // 8 MB [BH][T][HD]
    unsigned short* vT_ws = (unsigned short*)(ws + 16777216);  // 8 MB [BH][HD][T]
    unsigned short* wtp   = (unsigned short*)(ws + 25165824);  // 2 MB [C][C] bf16
    unsigned short* xb    = (unsigned short*)(ws + 27262976);  // 8 MB x as bf16
    unsigned short* y_ws  = (unsigned short*)(ws + 27262976);  // 8 MB (aliases xb; xb dead by then)
    unsigned short* wta   = (unsigned short*)(ws + 35651584);  // 6 MB [3C][C] bf16

    // 1) weight transposes f32 [K][N] -> bf16 [N][K]; x -> bf16
    k_transpose<<<dim3(N_QKV / 32, C_SZ / 32), dim3(32, 8), 0, stream>>>(w_attn, wta, C_SZ, N_QKV);
    k_transpose<<<dim3(C_SZ / 32, C_SZ / 32), dim3(32, 8), 0, stream>>>(w_proj, wtp, C_SZ, C_SZ);
    k_cvt<<<(M_SZ * C_SZ) / (256 * 8), 256, 0, stream>>>(x, xb);

    // 2) QKV GEMM -> Q/K row-major + V^T
    k_gemm<1><<<dim3(N_QKV / 128, M_SZ / 128), 256, 0, stream>>>(
        xb, wta, b_attn, nullptr, q_ws, k_ws, vT_ws, M_SZ, N_QKV, C_SZ);

    // 3) causal flash attention -> y bf16 [B][T][C]
    k_attn<<<dim3(1024), 256, 0, stream>>>(q_ws, k_ws, vT_ws, y_ws);

    // 4) proj GEMM: y @ w_proj + b_proj -> f32 out
    k_gemm<0><<<dim3(C_SZ / 128, M_SZ / 128), 256, 0, stream>>>(
        y_ws, wtp, b_proj, out, nullptr, nullptr, nullptr, M_SZ, C_SZ, C_SZ);
}

// Round 4
// 132.847 us; speedup vs baseline: 1.9651x; 1.0773x over previous
//
#include <hip/hip_runtime.h>
#include <hip/hip_bf16.h>
#include <stdint.h>

// Problem constants
#define B_SZ 2
#define T_SZ 2048
#define C_SZ 1024
#define H_SZ 16
#define HD   64
#define BH   (B_SZ * H_SZ)   // 32
#define M_SZ (B_SZ * T_SZ)   // 4096
#define N_QKV (3 * C_SZ)     // 3072

typedef __attribute__((ext_vector_type(8))) __bf16 bf16x8;
typedef __attribute__((ext_vector_type(4))) float f32x4;
typedef __attribute__((ext_vector_type(8))) unsigned short us8;
typedef __attribute__((ext_vector_type(4))) unsigned short us4;
typedef __attribute__((ext_vector_type(4))) unsigned int u32x4;

__device__ __forceinline__ unsigned short f2bf(float f) {
    unsigned int u = __builtin_bit_cast(unsigned int, f);
    u += 0x7fffu + ((u >> 16) & 1u);   // round-to-nearest-even
    return (unsigned short)(u >> 16);
}

// async global->LDS, 16B per lane; lds base must be wave-uniform (HW adds lane*16)
__device__ __forceinline__ void gll16(const unsigned short* g, unsigned short* l) {
    __builtin_amdgcn_global_load_lds(
        (const __attribute__((address_space(1))) unsigned int*)g,
        (__attribute__((address_space(3))) unsigned int*)l, 16, 0, 0);
}

// ---------------- transpose: f32 [K][N] -> bf16 [N][K] ----------------
__global__ __launch_bounds__(256) void k_transpose(const float* __restrict__ in,
                                                   unsigned short* __restrict__ out,
                                                   int K, int N) {
    __shared__ float tile[32][33];
    const int n0 = blockIdx.x * 32, k0 = blockIdx.y * 32;
    const int tx = threadIdx.x, ty = threadIdx.y;  // (32, 8)
    #pragma unroll
    for (int j = 0; j < 32; j += 8)
        tile[ty + j][tx] = in[(size_t)(k0 + ty + j) * N + (n0 + tx)];
    __syncthreads();
    #pragma unroll
    for (int j = 0; j < 32; j += 8)
        out[(size_t)(n0 + ty + j) * K + (k0 + tx)] = f2bf(tile[tx][ty + j]);
}

// ---------------- convert: f32 -> bf16, 8 elems/thread ----------------
__global__ __launch_bounds__(256) void k_cvt(const float* __restrict__ in,
                                             unsigned short* __restrict__ out) {
    const size_t i = ((size_t)blockIdx.x * 256 + threadIdx.x) * 8;
    f32x4 a = *(const f32x4*)(in + i);
    f32x4 b = *(const f32x4*)(in + i + 4);
    us8 o;
    #pragma unroll
    for (int j = 0; j < 4; ++j) { o[j] = f2bf(a[j]); o[4 + j] = f2bf(b[j]); }
    *(us8*)(out + i) = o;
}

// ---------------- GEMM: C[M,N] = A[M,K](bf16) @ Bt[N,K]^T + bias ----------------
// 1D grid with bijective XCD swizzle (T1); EPI 0: f32 out + bias.
// EPI 1: scatter bf16 into Q/K (row-major) and V^T.
template <int EPI>
__global__ __launch_bounds__(256) void k_gemm(const unsigned short* __restrict__ A,
                                              const unsigned short* __restrict__ Bt,
                                              const float* __restrict__ bias,
                                              float* __restrict__ Cout,
                                              unsigned short* __restrict__ q_ws,
                                              unsigned short* __restrict__ k_ws,
                                              unsigned short* __restrict__ vT_ws,
                                              int M, int N, int K, int NX) {
    __shared__ __attribute__((aligned(16))) unsigned short Ald[128 * 64];
    __shared__ __attribute__((aligned(16))) unsigned short Bld[128 * 64];
    const int tid = threadIdx.x;
    const int wid = tid >> 6, lane = tid & 63;
    const int wr = wid >> 1, wc = wid & 1;
    const int g = lane >> 4, l15 = lane & 15;
    // XCD-aware bijective swizzle (gridDim.x % 8 == 0)
    const int nwg = gridDim.x;
    const int wg = (blockIdx.x & 7) * (nwg >> 3) + (blockIdx.x >> 3);
    const int m0 = (wg / NX) * 128, n0 = (wg % NX) * 128;

    f32x4 acc[4][4];
    #pragma unroll
    for (int i = 0; i < 4; ++i)
        #pragma unroll
        for (int j = 0; j < 4; ++j) acc[i][j] = (f32x4){0.f, 0.f, 0.f, 0.f};

    for (int k0 = 0; k0 < K; k0 += 64) {
        __syncthreads();
        #pragma unroll
        for (int i = 0; i < 4; ++i) {
            int c = i * 256 + tid;
            int row = c >> 3;
            int colb = ((c & 7) << 4) ^ ((row & 7) << 4);   // pre-swizzled source col
            gll16(A  + (size_t)(m0 + row) * K + k0 + (colb >> 1), Ald + i * 2048 + wid * 512);
            gll16(Bt + (size_t)(n0 + row) * K + k0 + (colb >> 1), Bld + i * 2048 + wid * 512);
        }
        __syncthreads();

        #pragma unroll
        for (int ks = 0; ks < 2; ++ks) {
            bf16x8 af[4], bfr[4];
            #pragma unroll
            for (int mi = 0; mi < 4; ++mi) {
                int row = wr * 64 + mi * 16 + l15;
                af[mi] = *(const bf16x8*)((const char*)Ald + row * 128 +
                                          ((ks * 64 + g * 16) ^ ((row & 7) << 4)));
            }
            #pragma unroll
            for (int nj = 0; nj < 4; ++nj) {
                int row = wc * 64 + nj * 16 + l15;
                bfr[nj] = *(const bf16x8*)((const char*)Bld + row * 128 +
                                           ((ks * 64 + g * 16) ^ ((row & 7) << 4)));
            }
            #pragma unroll
            for (int mi = 0; mi < 4; ++mi)
                #pragma unroll
                for (int nj = 0; nj < 4; ++nj)
                    acc[mi][nj] = __builtin_amdgcn_mfma_f32_16x16x32_bf16(
                        af[mi], bfr[nj], acc[mi][nj], 0, 0, 0);
        }
    }

    if (EPI == 0) {
        #pragma unroll
        for (int nj = 0; nj < 4; ++nj) {
            int col = n0 + wc * 64 + nj * 16 + l15;
            float bv = bias[col];
            #pragma unroll
            for (int mi = 0; mi < 4; ++mi) {
                int rowb = m0 + wr * 64 + mi * 16 + g * 4;
                #pragma unroll
                for (int r = 0; r < 4; ++r)
                    Cout[(size_t)(rowb + r) * N + col] = acc[mi][nj][r] + bv;
            }
        }
    } else {
        #pragma unroll
        for (int nj = 0; nj < 4; ++nj) {
            int col = n0 + wc * 64 + nj * 16 + l15;   // 0..3071
            float bv = bias[col];
            int which = col >> 10;
            int c10 = col & 1023;
            int h = c10 >> 6, d = c10 & 63;
            #pragma unroll
            for (int mi = 0; mi < 4; ++mi) {
                #pragma unroll
                for (int r = 0; r < 4; ++r) {
                    int row = m0 + wr * 64 + mi * 16 + g * 4 + r;  // 0..4095
                    int bb = row >> 11, t = row & 2047;
                    unsigned short val = f2bf(acc[mi][nj][r] + bv);
                    if (which == 2)
                        vT_ws[((size_t)(bb * H_SZ + h) * HD + d) * T_SZ + t] = val;       // V^T
                    else
                        (which ? k_ws : q_ws)[((size_t)(bb * H_SZ + h) * T_SZ + t) * HD + d] = val;
                }
            }
        }
    }
}

// ---------------- causal flash attention ----------------
// Block mapping: i=n&7 (XCD), x=(n>>3)&31, k=n>>8 (round).
// bh = i + 8k  -> one head per XCD-round (K/V 1MB fits its L2).
// qb = {x, 31-x, (x+8)&31, (23-x)&31} by round -> every CU's 4 blocks sum to
// exactly 66 KV-steps (work balance).
__global__ __launch_bounds__(256) void k_attn(const unsigned short* __restrict__ q_ws,
                                              const unsigned short* __restrict__ k_ws,
                                              const unsigned short* __restrict__ vT_ws,
                                              unsigned short* __restrict__ y_ws) {
    __shared__ __attribute__((aligned(16))) unsigned short Kbuf[2][4096];
    __shared__ __attribute__((aligned(16))) unsigned short Vbuf[2][4096];
    const int tid = threadIdx.x;
    const int wid = tid >> 6, lane = tid & 63;
    const int g = lane >> 4, l15 = lane & 15;
    const int n = blockIdx.x;
    const int xcd = n & 7, x = (n >> 3) & 31, rk = n >> 8;
    const int bh = xcd + 8 * rk;
    int base = (rk & 2) ? ((x + 8) & 31) : x;
    const int qb = (rk & 1) ? (31 - base) : base;
    const size_t kv_off = (size_t)bh * T_SZ * HD;

    // Q fragments (rows = wave's 16 q rows); B-operand of mfma(K,Q)
    const int qrow = qb * 64 + wid * 16 + l15;
    bf16x8 aq[2];
    aq[0] = *(const bf16x8*)(q_ws + kv_off + (size_t)qrow * HD + g * 8);
    aq[1] = *(const bf16x8*)(q_ws + kv_off + (size_t)qrow * HD + 32 + g * 8);

    float m_run = -3e38f, l_run = 0.f;
    f32x4 acc[4];
    #pragma unroll
    for (int dt = 0; dt < 4; ++dt) acc[dt] = (f32x4){0.f, 0.f, 0.f, 0.f};

    const unsigned short* Kg = k_ws + kv_off;
    const unsigned short* Vg = vT_ws + (size_t)bh * HD * T_SZ;

    auto stageK = [&](int kv, int buf) {
        #pragma unroll
        for (int i = 0; i < 2; ++i) {
            int c = i * 256 + tid;
            int row = c >> 3;
            int colb = ((c & 7) << 4) ^ ((row & 7) << 4);
            gll16(Kg + (size_t)(kv * 64 + row) * HD + (colb >> 1),
                  &Kbuf[buf][i * 2048 + wid * 512]);
        }
    };
    auto stageV = [&](int kv, int buf) {
        #pragma unroll
        for (int i = 0; i < 2; ++i) {
            int c = i * 256 + tid;
            int row = c >> 3;                             // d index
            int colb = ((c & 7) << 4) ^ ((row & 7) << 4); // t-offset bytes in tile
            gll16(Vg + (size_t)row * T_SZ + kv * 64 + (colb >> 1),
                  &Vbuf[buf][i * 2048 + wid * 512]);
        }
    };

    stageK(0, 0); stageV(0, 0);
    int cur = 0;
    const int qloc = wid * 16 + l15;
    const float SC = 0.125f * 1.44269504f;  // 1/sqrt(64) * log2(e)

    for (int kv = 0; kv <= qb; ++kv) {
        __syncthreads();   // drains prefetch vmcnt; buf[cur] ready, buf[cur^1] free
        if (kv < qb) { stageK(kv + 1, cur ^ 1); stageV(kv + 1, cur ^ 1); }
        const char* Kb = (const char*)Kbuf[cur];
        const char* Vb = (const char*)Vbuf[cur];

        // S^T = K @ Q^T : D[row=key][col=q]; lane holds keys kt*16+4g+r for q=l15
        f32x4 st[4];
        __builtin_amdgcn_s_setprio(1);
        #pragma unroll
        for (int kt = 0; kt < 4; ++kt) {
            f32x4 sv = (f32x4){0.f, 0.f, 0.f, 0.f};
            #pragma unroll
            for (int ks = 0; ks < 2; ++ks) {
                int row = kt * 16 + l15;
                bf16x8 ak = *(const bf16x8*)(Kb + row * 128 +
                                             ((ks * 64 + g * 16) ^ ((row & 7) << 4)));
                sv = __builtin_amdgcn_mfma_f32_16x16x32_bf16(ak, aq[ks], sv, 0, 0, 0);
            }
            st[kt] = sv;
        }
        __builtin_amdgcn_s_setprio(0);

        // raw (unscaled) S with causal mask on the diagonal tile
        float t[16];
        #pragma unroll
        for (int kt = 0; kt < 4; ++kt)
            #pragma unroll
            for (int r = 0; r < 4; ++r) t[kt * 4 + r] = st[kt][r];
        if (kv == qb) {
            #pragma unroll
            for (int kt = 0; kt < 4; ++kt)
                #pragma unroll
                for (int r = 0; r < 4; ++r)
                    if ((kt * 16 + g * 4 + r) > qloc) t[kt * 4 + r] = -3e38f;
        }

        // tile max over raw S (15 fmax + 2 shfl), single scale mult
        float mx = t[0];
        #pragma unroll
        for (int i = 1; i < 16; ++i) mx = fmaxf(mx, t[i]);
        mx = fmaxf(mx, __shfl_xor(mx, 16, 64));
        mx = fmaxf(mx, __shfl_xor(mx, 32, 64));
        float mt = mx * SC;

        // defer-max (T13): only rescale when the tile max grew past THR=8
        if (!__all(mt - m_run <= 8.0f)) {
            float mnew = fmaxf(m_run, mt);
            float alpha = exp2f(m_run - mnew);
            m_run = mnew;
            l_run *= alpha;
            float ao[4];
            #pragma unroll
            for (int r = 0; r < 4; ++r) {
                int ai = __builtin_amdgcn_ds_bpermute((g * 4 + r) * 4,
                                                      __builtin_bit_cast(int, alpha));
                ao[r] = __builtin_bit_cast(float, ai);
            }
            #pragma unroll
            for (int dt = 0; dt < 4; ++dt)
                #pragma unroll
                for (int r = 0; r < 4; ++r) acc[dt][r] *= ao[r];
        }

        // p = exp2(S*SC - m) via fma; p bounded by 2^8
        float p[16], sum = 0.f;
        #pragma unroll
        for (int i = 0; i < 16; ++i) {
            p[i] = exp2f(fmaf(t[i], SC, -m_run));
            sum += p[i];
        }
        sum += __shfl_xor(sum, 16, 64);
        sum += __shfl_xor(sum, 32, 64);
        l_run += sum;

        // P -> bf16 pairs, then permlane swaps rebuild the A-fragment in-register
        unsigned int pk0[4], pk1[4];
        #pragma unroll
        for (int kt = 0; kt < 4; ++kt) {
            asm("v_cvt_pk_bf16_f32 %0, %1, %2" : "=v"(pk0[kt]) : "v"(p[kt * 4 + 0]), "v"(p[kt * 4 + 1]));
            asm("v_cvt_pk_bf16_f32 %0, %1, %2" : "=v"(pk1[kt]) : "v"(p[kt * 4 + 2]), "v"(p[kt * 4 + 3]));
        }
        __builtin_amdgcn_s_setprio(1);
        #pragma unroll
        for (int ks = 0; ks < 2; ++ks) {
            unsigned int x0 = pk0[2 * ks], y0 = pk0[2 * ks + 1];
            unsigned int x1 = pk1[2 * ks], y1 = pk1[2 * ks + 1];
            asm("v_permlane32_swap_b32 %0, %1" : "+v"(x0), "+v"(y0));
            asm("v_permlane16_swap_b32 %0, %1" : "+v"(x0), "+v"(y0));
            asm("v_permlane32_swap_b32 %0, %1" : "+v"(x1), "+v"(y1));
            asm("v_permlane16_swap_b32 %0, %1" : "+v"(x1), "+v"(y1));
            bf16x8 ap = __builtin_bit_cast(bf16x8, (u32x4){x0, x1, y0, y1});
            #pragma unroll
            for (int dt = 0; dt < 4; ++dt) {
                int row = dt * 16 + l15;
                bf16x8 bv = *(const bf16x8*)(Vb + row * 128 +
                                             ((ks * 64 + g * 16) ^ ((row & 7) << 4)));
                acc[dt] = __builtin_amdgcn_mfma_f32_16x16x32_bf16(ap, bv, acc[dt], 0, 0, 0);
            }
        }
        __builtin_amdgcn_s_setprio(0);
        cur ^= 1;
    }

    // epilogue: gather l for q=4g+r, normalize, store y[b,t,h*64+d]
    float lo[4];
    #pragma unroll
    for (int r = 0; r < 4; ++r) {
        int li = __builtin_amdgcn_ds_bpermute((g * 4 + r) * 4,
                                              __builtin_bit_cast(int, l_run));
        lo[r] = __builtin_bit_cast(float, li);
    }
    const int b = bh >> 4, h = bh & 15;
    #pragma unroll
    for (int r = 0; r < 4; ++r) {
        int tq = qb * 64 + wid * 16 + g * 4 + r;
        float inv = 1.0f / lo[r];
        #pragma unroll
        for (int dt = 0; dt < 4; ++dt)
            y_ws[(size_t)(b * T_SZ + tq) * C_SZ + h * 64 + dt * 16 + l15] =
                f2bf(acc[dt][r] * inv);
    }
}

// ---------------- launcher ----------------
extern "C" void kernel_launch(void* const* d_in, const int* in_sizes, int n_in,
                              void* d_out, int out_size, void* d_ws, size_t ws_size,
                              hipStream_t stream) {
    const float* x      = (const float*)d_in[0];
    const float* w_attn = (const float*)d_in[1];
    const float* b_attn = (const float*)d_in[2];
    const float* w_proj = (const float*)d_in[3];
    const float* b_proj = (const float*)d_in[4];
    float* out = (float*)d_out;

    // workspace layout (bytes), total 40 MB
    char* ws = (char*)d_ws;
    unsigned short* q_ws  = (unsigned short*)(ws + 0);         // 8 MB [BH][T][HD]
    unsigned short* k_ws  = (unsigned short*)(ws + 8388608);   // 8 MB [BH][T][HD]
    unsigned short* vT_ws = (unsigned short*)(ws + 16777216);  // 8 MB [BH][HD][T]
    unsigned short* wtp   = (unsigned short*)(ws + 25165824);  // 2 MB [C][C] bf16
    unsigned short* xb    = (unsigned short*)(ws + 27262976);  // 8 MB x as bf16
    unsigned short* y_ws  = (unsigned short*)(ws + 27262976);  // 8 MB (aliases xb; xb dead by then)
    unsigned short* wta   = (unsigned short*)(ws + 35651584);  // 6 MB [3C][C] bf16

    // 1) weight transposes f32 [K][N] -> bf16 [N][K]; x -> bf16
    k_transpose<<<dim3(N_QKV / 32, C_SZ / 32), dim3(32, 8), 0, stream>>>(w_attn, wta, C_SZ, N_QKV);
    k_transpose<<<dim3(C_SZ / 32, C_SZ / 32), dim3(32, 8), 0, stream>>>(w_proj, wtp, C_SZ, C_SZ);
    k_cvt<<<(M_SZ * C_SZ) / (256 * 8), 256, 0, stream>>>(x, xb);

    // 2) QKV GEMM -> Q/K row-major + V^T   (grid 768 = 24x32, %8==0)
    k_gemm<1><<<dim3((N_QKV / 128) * (M_SZ / 128)), 256, 0, stream>>>(
        xb, wta, b_attn, nullptr, q_ws, k_ws, vT_ws, M_SZ, N_QKV, C_SZ, N_QKV / 128);

    // 3) causal flash attention -> y bf16 [B][T][C]
    k_attn<<<dim3(1024), 256, 0, stream>>>(q_ws, k_ws, vT_ws, y_ws);

    // 4) proj GEMM: y @ w_proj + b_proj -> f32 out  (grid 256 = 8x32, %8==0)
    k_gemm<0><<<dim3((C_SZ / 128) * (M_SZ / 128)), 256, 0, stream>>>(
        y_ws, wtp, b_proj, out, nullptr, nullptr, nullptr, M_SZ, C_SZ, C_SZ, C_SZ / 128);
}

// Round 8
// 124.754 us; speedup vs baseline: 2.0925x; 1.0649x over previous
//
#include <hip/hip_runtime.h>
#include <hip/hip_bf16.h>
#include <stdint.h>

// Problem constants
#define B_SZ 2
#define T_SZ 2048
#define C_SZ 1024
#define H_SZ 16
#define HD   64
#define BH   (B_SZ * H_SZ)   // 32
#define M_SZ (B_SZ * T_SZ)   // 4096
#define N_QKV (3 * C_SZ)     // 3072

typedef __attribute__((ext_vector_type(8))) __bf16 bf16x8;
typedef __attribute__((ext_vector_type(4))) float f32x4;
typedef __attribute__((ext_vector_type(8))) unsigned short us8;
typedef __attribute__((ext_vector_type(4))) unsigned short us4;
typedef __attribute__((ext_vector_type(4))) unsigned int u32x4;

__device__ __forceinline__ unsigned short f2bf(float f) {
    unsigned int u = __builtin_bit_cast(unsigned int, f);
    u += 0x7fffu + ((u >> 16) & 1u);   // round-to-nearest-even
    return (unsigned short)(u >> 16);
}

// async global->LDS, 16B per lane; lds base must be wave-uniform (HW adds lane*16)
__device__ __forceinline__ void gll16(const unsigned short* g, unsigned short* l) {
    __builtin_amdgcn_global_load_lds(
        (const __attribute__((address_space(1))) unsigned int*)g,
        (__attribute__((address_space(3))) unsigned int*)l, 16, 0, 0);
}

// Barrier with EXPLICIT LDS-DMA drain. __syncthreads() alone relies on the
// compiler emitting s_waitcnt vmcnt(0) for in-flight global_load_lds before
// s_barrier; R7 showed timing-dependent divergence consistent with that drain
// being unreliable for our issue-after-barrier prefetch structure. Make it
// unconditional and un-hoistable (rule #18: sched_barrier after asm waitcnt).
__device__ __forceinline__ void hard_sync() {
    asm volatile("s_waitcnt vmcnt(0) lgkmcnt(0)" ::: "memory");
    __builtin_amdgcn_sched_barrier(0);
    __syncthreads();
}

// ---------------- prep: x->bf16 + both weight transposes (fused) ----------------
// grid: [0,2048) cvt x; [2048,5120) transpose w_attn; [5120,6144) transpose w_proj
__global__ __launch_bounds__(256) void k_prep(const float* __restrict__ x,
                                              const float* __restrict__ wa,
                                              const float* __restrict__ wp,
                                              unsigned short* __restrict__ xb,
                                              unsigned short* __restrict__ wta,
                                              unsigned short* __restrict__ wtp) {
    __shared__ float tile[32][33];
    const int tid = threadIdx.x;
    int idx = blockIdx.x;
    if (idx < 2048) {
        const size_t i = ((size_t)idx * 256 + tid) * 8;
        f32x4 a = *(const f32x4*)(x + i);
        f32x4 b = *(const f32x4*)(x + i + 4);
        us8 o;
        #pragma unroll
        for (int j = 0; j < 4; ++j) { o[j] = f2bf(a[j]); o[4 + j] = f2bf(b[j]); }
        *(us8*)(xb + i) = o;
        return;
    }
    const float* in; unsigned short* out; int N;
    if (idx < 5120) { idx -= 2048; in = wa; out = wta; N = N_QKV; }
    else            { idx -= 5120; in = wp; out = wtp; N = C_SZ; }
    const int nx = N / 32;
    const int n0 = (idx % nx) * 32, k0 = (idx / nx) * 32;
    const int tx = tid & 31, ty = tid >> 5;  // (32, 8)
    #pragma unroll
    for (int j = 0; j < 32; j += 8)
        tile[ty + j][tx] = in[(size_t)(k0 + ty + j) * N + (n0 + tx)];
    __syncthreads();
    #pragma unroll
    for (int j = 0; j < 32; j += 8)
        out[(size_t)(n0 + ty + j) * C_SZ + (k0 + tx)] = f2bf(tile[tx][ty + j]);
}

// ---------------- GEMM: C[M,N] = A[M,K](bf16) @ Bt[N,K]^T + bias ----------------
template <int EPI>
__global__ __launch_bounds__(256) void k_gemm(const unsigned short* __restrict__ A,
                                              const unsigned short* __restrict__ Bt,
                                              const float* __restrict__ bias,
                                              float* __restrict__ Cout,
                                              unsigned short* __restrict__ q_ws,
                                              unsigned short* __restrict__ k_ws,
                                              unsigned short* __restrict__ vT_ws,
                                              int M, int N, int K, int NX) {
    __shared__ __attribute__((aligned(16))) unsigned short Ald[128 * 64];
    __shared__ __attribute__((aligned(16))) unsigned short Bld[128 * 64];
    const int tid = threadIdx.x;
    const int wid = tid >> 6, lane = tid & 63;
    const int wr = wid >> 1, wc = wid & 1;
    const int g = lane >> 4, l15 = lane & 15;
    const int nwg = gridDim.x;
    const int wg = (blockIdx.x & 7) * (nwg >> 3) + (blockIdx.x >> 3);
    const int m0 = (wg / NX) * 128, n0 = (wg % NX) * 128;

    f32x4 acc[4][4];
    #pragma unroll
    for (int i = 0; i < 4; ++i)
        #pragma unroll
        for (int j = 0; j < 4; ++j) acc[i][j] = (f32x4){0.f, 0.f, 0.f, 0.f};

    for (int k0 = 0; k0 < K; k0 += 64) {
        hard_sync();
        #pragma unroll
        for (int i = 0; i < 4; ++i) {
            int c = i * 256 + tid;
            int row = c >> 3;
            int colb = ((c & 7) << 4) ^ ((row & 7) << 4);
            gll16(A  + (size_t)(m0 + row) * K + k0 + (colb >> 1), Ald + i * 2048 + wid * 512);
            gll16(Bt + (size_t)(n0 + row) * K + k0 + (colb >> 1), Bld + i * 2048 + wid * 512);
        }
        hard_sync();

        #pragma unroll
        for (int ks = 0; ks < 2; ++ks) {
            bf16x8 af[4], bfr[4];
            #pragma unroll
            for (int mi = 0; mi < 4; ++mi) {
                int row = wr * 64 + mi * 16 + l15;
                af[mi] = *(const bf16x8*)((const char*)Ald + row * 128 +
                                          ((ks * 64 + g * 16) ^ ((row & 7) << 4)));
            }
            #pragma unroll
            for (int nj = 0; nj < 4; ++nj) {
                int row = wc * 64 + nj * 16 + l15;
                bfr[nj] = *(const bf16x8*)((const char*)Bld + row * 128 +
                                           ((ks * 64 + g * 16) ^ ((row & 7) << 4)));
            }
            #pragma unroll
            for (int mi = 0; mi < 4; ++mi)
                #pragma unroll
                for (int nj = 0; nj < 4; ++nj)
                    acc[mi][nj] = __builtin_amdgcn_mfma_f32_16x16x32_bf16(
                        af[mi], bfr[nj], acc[mi][nj], 0, 0, 0);
        }
    }

    if (EPI == 0) {
        #pragma unroll
        for (int nj = 0; nj < 4; ++nj) {
            int col = n0 + wc * 64 + nj * 16 + l15;
            float bv = bias[col];
            #pragma unroll
            for (int mi = 0; mi < 4; ++mi) {
                int rowb = m0 + wr * 64 + mi * 16 + g * 4;
                #pragma unroll
                for (int r = 0; r < 4; ++r)
                    Cout[(size_t)(rowb + r) * N + col] = acc[mi][nj][r] + bv;
            }
        }
    } else {
        #pragma unroll
        for (int nj = 0; nj < 4; ++nj) {
            int col = n0 + wc * 64 + nj * 16 + l15;   // 0..3071
            float bv = bias[col];
            int which = col >> 10;
            int c10 = col & 1023;
            int h = c10 >> 6, d = c10 & 63;
            #pragma unroll
            for (int mi = 0; mi < 4; ++mi) {
                #pragma unroll
                for (int r = 0; r < 4; ++r) {
                    int row = m0 + wr * 64 + mi * 16 + g * 4 + r;  // 0..4095
                    int bb = row >> 11, t = row & 2047;
                    unsigned short val = f2bf(acc[mi][nj][r] + bv);
                    if (which == 2)
                        vT_ws[((size_t)(bb * H_SZ + h) * HD + d) * T_SZ + t] = val;       // V^T
                    else
                        (which ? k_ws : q_ws)[((size_t)(bb * H_SZ + h) * T_SZ + t) * HD + d] = val;
                }
            }
        }
    }
}

// ---------------- causal flash attention ----------------
// Block mapping: i=n&7 (XCD), x=(n>>3)&31, k=n>>8 (round).
// bh = i + 8k; qb = {x, 31-x, (x+8)&31, (23-x)&31} by round.
__global__ __launch_bounds__(256) void k_attn(const unsigned short* __restrict__ q_ws,
                                              const unsigned short* __restrict__ k_ws,
                                              const unsigned short* __restrict__ vT_ws,
                                              unsigned short* __restrict__ y_ws) {
    __shared__ __attribute__((aligned(16))) unsigned short Kbuf[2][4096];
    __shared__ __attribute__((aligned(16))) unsigned short Vbuf[2][4096];
    const int tid = threadIdx.x;
    const int wid = tid >> 6, lane = tid & 63;
    const int g = lane >> 4, l15 = lane & 15;
    const int n = blockIdx.x;
    const int xcd = n & 7, x = (n >> 3) & 31, rk = n >> 8;
    const int bh = xcd + 8 * rk;
    int base = (rk & 2) ? ((x + 8) & 31) : x;
    const int qb = (rk & 1) ? (31 - base) : base;
    const size_t kv_off = (size_t)bh * T_SZ * HD;

    // Q fragments (rows = wave's 16 q rows); B-operand of mfma(K,Q)
    const int qrow = qb * 64 + wid * 16 + l15;
    bf16x8 aq[2];
    aq[0] = *(const bf16x8*)(q_ws + kv_off + (size_t)qrow * HD + g * 8);
    aq[1] = *(const bf16x8*)(q_ws + kv_off + (size_t)qrow * HD + 32 + g * 8);

    float m_run = -3e38f, l_run = 0.f;
    f32x4 acc[4];
    #pragma unroll
    for (int dt = 0; dt < 4; ++dt) acc[dt] = (f32x4){0.f, 0.f, 0.f, 0.f};

    const unsigned short* Kg = k_ws + kv_off;
    const unsigned short* Vg = vT_ws + (size_t)bh * HD * T_SZ;

    auto stageK = [&](int kv, int buf) {
        #pragma unroll
        for (int i = 0; i < 2; ++i) {
            int c = i * 256 + tid;
            int row = c >> 3;
            int colb = ((c & 7) << 4) ^ ((row & 7) << 4);
            gll16(Kg + (size_t)(kv * 64 + row) * HD + (colb >> 1),
                  &Kbuf[buf][i * 2048 + wid * 512]);
        }
    };
    auto stageV = [&](int kv, int buf) {
        #pragma unroll
        for (int i = 0; i < 2; ++i) {
            int c = i * 256 + tid;
            int row = c >> 3;                             // d index
            int colb = ((c & 7) << 4) ^ ((row & 7) << 4); // t-offset bytes
            gll16(Vg + (size_t)row * T_SZ + kv * 64 + (colb >> 1),
                  &Vbuf[buf][i * 2048 + wid * 512]);
        }
    };

    stageK(0, 0); stageV(0, 0);
    int cur = 0;
    const int qloc = wid * 16 + l15;
    const float SC = 0.125f * 1.44269504f;  // 1/sqrt(64) * log2(e)

    for (int kv = 0; kv <= qb; ++kv) {
        hard_sync();   // explicit vmcnt(0) drain: buf[cur] ready, buf[cur^1] free
        if (kv < qb) { stageK(kv + 1, cur ^ 1); stageV(kv + 1, cur ^ 1); }
        const char* Kb = (const char*)Kbuf[cur];
        const char* Vb = (const char*)Vbuf[cur];

        // S^T = K @ Q^T : lane holds keys kt*16+4g+r for q=l15
        f32x4 st[4];
        __builtin_amdgcn_s_setprio(1);
        #pragma unroll
        for (int kt = 0; kt < 4; ++kt) {
            f32x4 sv = (f32x4){0.f, 0.f, 0.f, 0.f};
            #pragma unroll
            for (int ks = 0; ks < 2; ++ks) {
                int row = kt * 16 + l15;
                bf16x8 ak = *(const bf16x8*)(Kb + row * 128 +
                                             ((ks * 64 + g * 16) ^ ((row & 7) << 4)));
                sv = __builtin_amdgcn_mfma_f32_16x16x32_bf16(ak, aq[ks], sv, 0, 0, 0);
            }
            st[kt] = sv;
        }
        __builtin_amdgcn_s_setprio(0);

        // raw (unscaled) S with causal mask on the diagonal tile
        float t[16];
        #pragma unroll
        for (int kt = 0; kt < 4; ++kt)
            #pragma unroll
            for (int r = 0; r < 4; ++r) t[kt * 4 + r] = st[kt][r];
        if (kv == qb) {
            #pragma unroll
            for (int kt = 0; kt < 4; ++kt)
                #pragma unroll
                for (int r = 0; r < 4; ++r)
                    if ((kt * 16 + g * 4 + r) > qloc) t[kt * 4 + r] = -3e38f;
        }

        // tile max over raw S (15 fmax + 2 shfl), single scale mult
        float mx = t[0];
        #pragma unroll
        for (int i = 1; i < 16; ++i) mx = fmaxf(mx, t[i]);
        mx = fmaxf(mx, __shfl_xor(mx, 16, 64));
        mx = fmaxf(mx, __shfl_xor(mx, 32, 64));
        float mt = mx * SC;

        // defer-max (T13): only rescale when the tile max grew past THR=8
        if (!__all(mt - m_run <= 8.0f)) {
            float mnew = fmaxf(m_run, mt);
            float alpha = exp2f(m_run - mnew);
            m_run = mnew;
            l_run *= alpha;
            float ao[4];
            #pragma unroll
            for (int r = 0; r < 4; ++r) {
                int ai = __builtin_amdgcn_ds_bpermute((g * 4 + r) * 4,
                                                      __builtin_bit_cast(int, alpha));
                ao[r] = __builtin_bit_cast(float, ai);
            }
            #pragma unroll
            for (int dt = 0; dt < 4; ++dt)
                #pragma unroll
                for (int r = 0; r < 4; ++r) acc[dt][r] *= ao[r];
        }

        // p = exp2(S*SC - m) via fma; p bounded by 2^8
        float p[16], sum = 0.f;
        #pragma unroll
        for (int i = 0; i < 16; ++i) {
            p[i] = exp2f(fmaf(t[i], SC, -m_run));
            sum += p[i];
        }
        sum += __shfl_xor(sum, 16, 64);
        sum += __shfl_xor(sum, 32, 64);
        l_run += sum;

        // P -> bf16 pairs, then permlane swaps rebuild the A-fragment in-register
        unsigned int pk0[4], pk1[4];
        #pragma unroll
        for (int kt = 0; kt < 4; ++kt) {
            asm("v_cvt_pk_bf16_f32 %0, %1, %2" : "=v"(pk0[kt]) : "v"(p[kt * 4 + 0]), "v"(p[kt * 4 + 1]));
            asm("v_cvt_pk_bf16_f32 %0, %1, %2" : "=v"(pk1[kt]) : "v"(p[kt * 4 + 2]), "v"(p[kt * 4 + 3]));
        }
        __builtin_amdgcn_s_setprio(1);
        #pragma unroll
        for (int ks = 0; ks < 2; ++ks) {
            unsigned int x0 = pk0[2 * ks], y0 = pk0[2 * ks + 1];
            unsigned int x1 = pk1[2 * ks], y1 = pk1[2 * ks + 1];
            asm("v_permlane32_swap_b32 %0, %1" : "+v"(x0), "+v"(y0));
            asm("v_permlane16_swap_b32 %0, %1" : "+v"(x0), "+v"(y0));
            asm("v_permlane32_swap_b32 %0, %1" : "+v"(x1), "+v"(y1));
            asm("v_permlane16_swap_b32 %0, %1" : "+v"(x1), "+v"(y1));
            bf16x8 ap = __builtin_bit_cast(bf16x8, (u32x4){x0, x1, y0, y1});
            #pragma unroll
            for (int dt = 0; dt < 4; ++dt) {
                int row = dt * 16 + l15;
                bf16x8 bv = *(const bf16x8*)(Vb + row * 128 +
                                             ((ks * 64 + g * 16) ^ ((row & 7) << 4)));
                acc[dt] = __builtin_amdgcn_mfma_f32_16x16x32_bf16(ap, bv, acc[dt], 0, 0, 0);
            }
        }
        __builtin_amdgcn_s_setprio(0);
        cur ^= 1;
    }

    // epilogue: gather l for q=4g+r, normalize, store y[b,t,h*64+d]
    float lo[4];
    #pragma unroll
    for (int r = 0; r < 4; ++r) {
        int li = __builtin_amdgcn_ds_bpermute((g * 4 + r) * 4,
                                              __builtin_bit_cast(int, l_run));
        lo[r] = __builtin_bit_cast(float, li);
    }
    const int b = bh >> 4, h = bh & 15;
    #pragma unroll
    for (int r = 0; r < 4; ++r) {
        int tq = qb * 64 + wid * 16 + g * 4 + r;
        float inv = 1.0f / lo[r];
        #pragma unroll
        for (int dt = 0; dt < 4; ++dt)
            y_ws[(size_t)(b * T_SZ + tq) * C_SZ + h * 64 + dt * 16 + l15] =
                f2bf(acc[dt][r] * inv);
    }
}

// ---------------- launcher ----------------
extern "C" void kernel_launch(void* const* d_in, const int* in_sizes, int n_in,
                              void* d_out, int out_size, void* d_ws, size_t ws_size,
                              hipStream_t stream) {
    const float* x      = (const float*)d_in[0];
    const float* w_attn = (const float*)d_in[1];
    const float* b_attn = (const float*)d_in[2];
    const float* w_proj = (const float*)d_in[3];
    const float* b_proj = (const float*)d_in[4];
    float* out = (float*)d_out;

    char* ws = (char*)d_ws;
    unsigned short* q_ws  = (unsigned short*)(ws + 0);         // 8 MB [BH][T][HD]
    unsigned short* k_ws  = (unsigned short*)(ws + 8388608);   // 8 MB [BH][T][HD]
    unsigned short* vT_ws = (unsigned short*)(ws + 16777216);  // 8 MB [BH][HD][T]
    unsigned short* wtp   = (unsigned short*)(ws + 25165824);  // 2 MB [C][C]
    unsigned short* xb    = (unsigned short*)(ws + 27262976);  // 8 MB x as bf16
    unsigned short* y_ws  = (unsigned short*)(ws + 27262976);  // aliases xb (xb dead by then)
    unsigned short* wta   = (unsigned short*)(ws + 35651584);  // 6 MB [3C][C]

    // 1) fused prep: x->bf16 + both weight transposes
    k_prep<<<dim3(6144), 256, 0, stream>>>(x, w_attn, w_proj, xb, wta, wtp);

    // 2) QKV GEMM -> Q/K row-major + V^T   (grid 768, %8==0)
    k_gemm<1><<<dim3((N_QKV / 128) * (M_SZ / 128)), 256, 0, stream>>>(
        xb, wta, b_attn, nullptr, q_ws, k_ws, vT_ws, M_SZ, N_QKV, C_SZ, N_QKV / 128);

    // 3) causal flash attention -> y bf16 [B][T][C]
    k_attn<<<dim3(1024), 256, 0, stream>>>(q_ws, k_ws, vT_ws, y_ws);

    // 4) proj GEMM: y @ w_proj + b_proj -> f32 out  (grid 256, %8==0)
    k_gemm<0><<<dim3((C_SZ / 128) * (M_SZ / 128)), 256, 0, stream>>>(
        y_ws, wtp, b_proj, out, nullptr, nullptr, nullptr, M_SZ, C_SZ, C_SZ, C_SZ / 128);
}

// Round 9
// 123.023 us; speedup vs baseline: 2.1220x; 1.0141x over previous
//
#include <hip/hip_runtime.h>
#include <hip/hip_bf16.h>
#include <stdint.h>

// Problem constants
#define B_SZ 2
#define T_SZ 2048
#define C_SZ 1024
#define H_SZ 16
#define HD   64
#define BH   (B_SZ * H_SZ)   // 32
#define M_SZ (B_SZ * T_SZ)   // 4096
#define N_QKV (3 * C_SZ)     // 3072

typedef __attribute__((ext_vector_type(8))) __bf16 bf16x8;
typedef __attribute__((ext_vector_type(4))) float f32x4;
typedef __attribute__((ext_vector_type(8))) unsigned short us8;
typedef __attribute__((ext_vector_type(4))) unsigned short us4;
typedef __attribute__((ext_vector_type(4))) unsigned int u32x4;

__device__ __forceinline__ unsigned short f2bf(float f) {
    unsigned int u = __builtin_bit_cast(unsigned int, f);
    u += 0x7fffu + ((u >> 16) & 1u);   // round-to-nearest-even
    return (unsigned short)(u >> 16);
}

// async global->LDS, 16B per lane; lds base must be wave-uniform (HW adds lane*16)
__device__ __forceinline__ void gll16(const unsigned short* g, unsigned short* l) {
    __builtin_amdgcn_global_load_lds(
        (const __attribute__((address_space(1))) unsigned int*)g,
        (__attribute__((address_space(3))) unsigned int*)l, 16, 0, 0);
}

// Barrier with EXPLICIT LDS-DMA drain (R7/R8 lesson: __syncthreads alone is not
// a reliable vmcnt(0) drain for in-flight global_load_lds in this structure).
__device__ __forceinline__ void hard_sync() {
    asm volatile("s_waitcnt vmcnt(0) lgkmcnt(0)" ::: "memory");
    __builtin_amdgcn_sched_barrier(0);
    __syncthreads();
}

// ---------------- prep: x->bf16 + both weight transposes (fused) ----------------
// grid: [0,2048) cvt x; [2048,5120) transpose w_attn; [5120,6144) transpose w_proj
__global__ __launch_bounds__(256) void k_prep(const float* __restrict__ x,
                                              const float* __restrict__ wa,
                                              const float* __restrict__ wp,
                                              unsigned short* __restrict__ xb,
                                              unsigned short* __restrict__ wta,
                                              unsigned short* __restrict__ wtp) {
    __shared__ float tile[32][33];
    const int tid = threadIdx.x;
    int idx = blockIdx.x;
    if (idx < 2048) {
        const size_t i = ((size_t)idx * 256 + tid) * 8;
        f32x4 a = *(const f32x4*)(x + i);
        f32x4 b = *(const f32x4*)(x + i + 4);
        us8 o;
        #pragma unroll
        for (int j = 0; j < 4; ++j) { o[j] = f2bf(a[j]); o[4 + j] = f2bf(b[j]); }
        *(us8*)(xb + i) = o;
        return;
    }
    const float* in; unsigned short* out; int N;
    if (idx < 5120) { idx -= 2048; in = wa; out = wta; N = N_QKV; }
    else            { idx -= 5120; in = wp; out = wtp; N = C_SZ; }
    const int nx = N / 32;
    const int n0 = (idx % nx) * 32, k0 = (idx / nx) * 32;
    const int tx = tid & 31, ty = tid >> 5;  // (32, 8)
    #pragma unroll
    for (int j = 0; j < 32; j += 8)
        tile[ty + j][tx] = in[(size_t)(k0 + ty + j) * N + (n0 + tx)];
    __syncthreads();
    #pragma unroll
    for (int j = 0; j < 32; j += 8)
        out[(size_t)(n0 + ty + j) * C_SZ + (k0 + tx)] = f2bf(tile[tx][ty + j]);
}

// ---------------- GEMM: C[M,N] = A[M,K](bf16) @ Bt[N,K]^T + bias ----------------
template <int EPI>
__global__ __launch_bounds__(256) void k_gemm(const unsigned short* __restrict__ A,
                                              const unsigned short* __restrict__ Bt,
                                              const float* __restrict__ bias,
                                              float* __restrict__ Cout,
                                              unsigned short* __restrict__ q_ws,
                                              unsigned short* __restrict__ k_ws,
                                              unsigned short* __restrict__ vT_ws,
                                              int M, int N, int K, int NX) {
    __shared__ __attribute__((aligned(16))) unsigned short Ald[128 * 64];
    __shared__ __attribute__((aligned(16))) unsigned short Bld[128 * 64];
    const int tid = threadIdx.x;
    const int wid = tid >> 6, lane = tid & 63;
    const int wr = wid >> 1, wc = wid & 1;
    const int g = lane >> 4, l15 = lane & 15;
    const int nwg = gridDim.x;
    const int wg = (blockIdx.x & 7) * (nwg >> 3) + (blockIdx.x >> 3);
    const int m0 = (wg / NX) * 128, n0 = (wg % NX) * 128;

    f32x4 acc[4][4];
    #pragma unroll
    for (int i = 0; i < 4; ++i)
        #pragma unroll
        for (int j = 0; j < 4; ++j) acc[i][j] = (f32x4){0.f, 0.f, 0.f, 0.f};

    for (int k0 = 0; k0 < K; k0 += 64) {
        hard_sync();
        #pragma unroll
        for (int i = 0; i < 4; ++i) {
            int c = i * 256 + tid;
            int row = c >> 3;
            int colb = ((c & 7) << 4) ^ ((row & 7) << 4);
            gll16(A  + (size_t)(m0 + row) * K + k0 + (colb >> 1), Ald + i * 2048 + wid * 512);
            gll16(Bt + (size_t)(n0 + row) * K + k0 + (colb >> 1), Bld + i * 2048 + wid * 512);
        }
        hard_sync();

        #pragma unroll
        for (int ks = 0; ks < 2; ++ks) {
            bf16x8 af[4], bfr[4];
            #pragma unroll
            for (int mi = 0; mi < 4; ++mi) {
                int row = wr * 64 + mi * 16 + l15;
                af[mi] = *(const bf16x8*)((const char*)Ald + row * 128 +
                                          ((ks * 64 + g * 16) ^ ((row & 7) << 4)));
            }
            #pragma unroll
            for (int nj = 0; nj < 4; ++nj) {
                int row = wc * 64 + nj * 16 + l15;
                bfr[nj] = *(const bf16x8*)((const char*)Bld + row * 128 +
                                           ((ks * 64 + g * 16) ^ ((row & 7) << 4)));
            }
            #pragma unroll
            for (int mi = 0; mi < 4; ++mi)
                #pragma unroll
                for (int nj = 0; nj < 4; ++nj)
                    acc[mi][nj] = __builtin_amdgcn_mfma_f32_16x16x32_bf16(
                        af[mi], bfr[nj], acc[mi][nj], 0, 0, 0);
        }
    }

    if (EPI == 0) {
        #pragma unroll
        for (int nj = 0; nj < 4; ++nj) {
            int col = n0 + wc * 64 + nj * 16 + l15;
            float bv = bias[col];
            #pragma unroll
            for (int mi = 0; mi < 4; ++mi) {
                int rowb = m0 + wr * 64 + mi * 16 + g * 4;
                #pragma unroll
                for (int r = 0; r < 4; ++r)
                    Cout[(size_t)(rowb + r) * N + col] = acc[mi][nj][r] + bv;
            }
        }
    } else {
        #pragma unroll
        for (int nj = 0; nj < 4; ++nj) {
            int col = n0 + wc * 64 + nj * 16 + l15;   // 0..3071
            float bv = bias[col];
            int which = col >> 10;
            int c10 = col & 1023;
            int h = c10 >> 6, d = c10 & 63;
            #pragma unroll
            for (int mi = 0; mi < 4; ++mi) {
                #pragma unroll
                for (int r = 0; r < 4; ++r) {
                    int row = m0 + wr * 64 + mi * 16 + g * 4 + r;  // 0..4095
                    int bb = row >> 11, t = row & 2047;
                    unsigned short val = f2bf(acc[mi][nj][r] + bv);
                    if (which == 2)
                        vT_ws[((size_t)(bb * H_SZ + h) * HD + d) * T_SZ + t] = val;       // V^T
                    else
                        (which ? k_ws : q_ws)[((size_t)(bb * H_SZ + h) * T_SZ + t) * HD + d] = val;
                }
            }
        }
    }
}

// ---------------- causal flash attention ----------------
// 512 blocks: xcd=n&7, j=(n>>3)&15, rk=n>>7. bh = xcd + 8*rk (head-per-XCD L2
// clustering). Each block processes q-tile pair {31-j, j} sequentially ->
// exactly 33 KV-steps per block, 2 blocks/CU all-resident, uniform finish.
__global__ __launch_bounds__(256) void k_attn(const unsigned short* __restrict__ q_ws,
                                              const unsigned short* __restrict__ k_ws,
                                              const unsigned short* __restrict__ vT_ws,
                                              unsigned short* __restrict__ y_ws) {
    __shared__ __attribute__((aligned(16))) unsigned short Kbuf[2][4096];
    __shared__ __attribute__((aligned(16))) unsigned short Vbuf[2][4096];
    const int tid = threadIdx.x;
    const int wid = tid >> 6, lane = tid & 63;
    const int g = lane >> 4, l15 = lane & 15;
    const int n = blockIdx.x;
    const int xcd = n & 7, j = (n >> 3) & 15, rk = n >> 7;
    const int bh = xcd + 8 * rk;
    const size_t kv_off = (size_t)bh * T_SZ * HD;
    const unsigned short* Kg = k_ws + kv_off;
    const unsigned short* Vg = vT_ws + (size_t)bh * HD * T_SZ;
    const int b = bh >> 4, h = bh & 15;
    const float SC = 0.125f * 1.44269504f;  // 1/sqrt(64) * log2(e)
    const int qloc = wid * 16 + l15;

    auto stageK = [&](int kv, int buf) {
        #pragma unroll
        for (int i = 0; i < 2; ++i) {
            int c = i * 256 + tid;
            int row = c >> 3;
            int colb = ((c & 7) << 4) ^ ((row & 7) << 4);
            gll16(Kg + (size_t)(kv * 64 + row) * HD + (colb >> 1),
                  &Kbuf[buf][i * 2048 + wid * 512]);
        }
    };
    auto stageV = [&](int kv, int buf) {
        #pragma unroll
        for (int i = 0; i < 2; ++i) {
            int c = i * 256 + tid;
            int row = c >> 3;                             // d index
            int colb = ((c & 7) << 4) ^ ((row & 7) << 4); // t-offset bytes
            gll16(Vg + (size_t)row * T_SZ + kv * 64 + (colb >> 1),
                  &Vbuf[buf][i * 2048 + wid * 512]);
        }
    };

    #pragma unroll 1
    for (int phase = 0; phase < 2; ++phase) {
        const int qb = phase ? j : (31 - j);

        // Q fragments for this phase
        const int qrow = qb * 64 + wid * 16 + l15;
        bf16x8 aq[2];
        aq[0] = *(const bf16x8*)(q_ws + kv_off + (size_t)qrow * HD + g * 8);
        aq[1] = *(const bf16x8*)(q_ws + kv_off + (size_t)qrow * HD + 32 + g * 8);

        float m_run = -3e38f, l_run = 0.f;
        f32x4 acc[4];
        #pragma unroll
        for (int dt = 0; dt < 4; ++dt) acc[dt] = (f32x4){0.f, 0.f, 0.f, 0.f};

        hard_sync();              // all waves done reading buffers (prev phase)
        stageK(0, 0); stageV(0, 0);
        int cur = 0;

        for (int kv = 0; kv <= qb; ++kv) {
            hard_sync();          // drain DMA: buf[cur] ready, buf[cur^1] free
            if (kv < qb) { stageK(kv + 1, cur ^ 1); stageV(kv + 1, cur ^ 1); }
            const char* Kb = (const char*)Kbuf[cur];
            const char* Vb = (const char*)Vbuf[cur];

            // S^T = K @ Q^T : lane holds keys kt*16+4g+r for q=l15
            f32x4 st[4];
            __builtin_amdgcn_s_setprio(1);
            #pragma unroll
            for (int kt = 0; kt < 4; ++kt) {
                f32x4 sv = (f32x4){0.f, 0.f, 0.f, 0.f};
                #pragma unroll
                for (int ks = 0; ks < 2; ++ks) {
                    int row = kt * 16 + l15;
                    bf16x8 ak = *(const bf16x8*)(Kb + row * 128 +
                                                 ((ks * 64 + g * 16) ^ ((row & 7) << 4)));
                    sv = __builtin_amdgcn_mfma_f32_16x16x32_bf16(ak, aq[ks], sv, 0, 0, 0);
                }
                st[kt] = sv;
            }
            __builtin_amdgcn_s_setprio(0);

            // raw (unscaled) S with causal mask on the diagonal tile
            float t[16];
            #pragma unroll
            for (int kt = 0; kt < 4; ++kt)
                #pragma unroll
                for (int r = 0; r < 4; ++r) t[kt * 4 + r] = st[kt][r];
            if (kv == qb) {
                #pragma unroll
                for (int kt = 0; kt < 4; ++kt)
                    #pragma unroll
                    for (int r = 0; r < 4; ++r)
                        if ((kt * 16 + g * 4 + r) > qloc) t[kt * 4 + r] = -3e38f;
            }

            // tile max over raw S (15 fmax + 2 shfl), single scale mult
            float mx = t[0];
            #pragma unroll
            for (int i = 1; i < 16; ++i) mx = fmaxf(mx, t[i]);
            mx = fmaxf(mx, __shfl_xor(mx, 16, 64));
            mx = fmaxf(mx, __shfl_xor(mx, 32, 64));
            float mt = mx * SC;

            // defer-max (T13): only rescale when the tile max grew past THR=8
            if (!__all(mt - m_run <= 8.0f)) {
                float mnew = fmaxf(m_run, mt);
                float alpha = exp2f(m_run - mnew);
                m_run = mnew;
                l_run *= alpha;
                float ao[4];
                #pragma unroll
                for (int r = 0; r < 4; ++r) {
                    int ai = __builtin_amdgcn_ds_bpermute((g * 4 + r) * 4,
                                                          __builtin_bit_cast(int, alpha));
                    ao[r] = __builtin_bit_cast(float, ai);
                }
                #pragma unroll
                for (int dt = 0; dt < 4; ++dt)
                    #pragma unroll
                    for (int r = 0; r < 4; ++r) acc[dt][r] *= ao[r];
            }

            // p = exp2(S*SC - m) via fma; p bounded by 2^8
            float p[16], sum = 0.f;
            #pragma unroll
            for (int i = 0; i < 16; ++i) {
                p[i] = exp2f(fmaf(t[i], SC, -m_run));
                sum += p[i];
            }
            sum += __shfl_xor(sum, 16, 64);
            sum += __shfl_xor(sum, 32, 64);
            l_run += sum;

            // P -> bf16 pairs, then permlane swaps rebuild the A-fragment
            unsigned int pk0[4], pk1[4];
            #pragma unroll
            for (int kt = 0; kt < 4; ++kt) {
                asm("v_cvt_pk_bf16_f32 %0, %1, %2" : "=v"(pk0[kt]) : "v"(p[kt * 4 + 0]), "v"(p[kt * 4 + 1]));
                asm("v_cvt_pk_bf16_f32 %0, %1, %2" : "=v"(pk1[kt]) : "v"(p[kt * 4 + 2]), "v"(p[kt * 4 + 3]));
            }
            __builtin_amdgcn_s_setprio(1);
            #pragma unroll
            for (int ks = 0; ks < 2; ++ks) {
                unsigned int x0 = pk0[2 * ks], y0 = pk0[2 * ks + 1];
                unsigned int x1 = pk1[2 * ks], y1 = pk1[2 * ks + 1];
                asm("v_permlane32_swap_b32 %0, %1" : "+v"(x0), "+v"(y0));
                asm("v_permlane16_swap_b32 %0, %1" : "+v"(x0), "+v"(y0));
                asm("v_permlane32_swap_b32 %0, %1" : "+v"(x1), "+v"(y1));
                asm("v_permlane16_swap_b32 %0, %1" : "+v"(x1), "+v"(y1));
                bf16x8 ap = __builtin_bit_cast(bf16x8, (u32x4){x0, x1, y0, y1});
                #pragma unroll
                for (int dt = 0; dt < 4; ++dt) {
                    int row = dt * 16 + l15;
                    bf16x8 bv = *(const bf16x8*)(Vb + row * 128 +
                                                 ((ks * 64 + g * 16) ^ ((row & 7) << 4)));
                    acc[dt] = __builtin_amdgcn_mfma_f32_16x16x32_bf16(ap, bv, acc[dt], 0, 0, 0);
                }
            }
            __builtin_amdgcn_s_setprio(0);
            cur ^= 1;
        }

        // epilogue: gather l for q=4g+r, normalize, store y[b,t,h*64+d]
        float lo[4];
        #pragma unroll
        for (int r = 0; r < 4; ++r) {
            int li = __builtin_amdgcn_ds_bpermute((g * 4 + r) * 4,
                                                  __builtin_bit_cast(int, l_run));
            lo[r] = __builtin_bit_cast(float, li);
        }
        #pragma unroll
        for (int r = 0; r < 4; ++r) {
            int tq = qb * 64 + wid * 16 + g * 4 + r;
            float inv = 1.0f / lo[r];
            #pragma unroll
            for (int dt = 0; dt < 4; ++dt)
                y_ws[(size_t)(b * T_SZ + tq) * C_SZ + h * 64 + dt * 16 + l15] =
                    f2bf(acc[dt][r] * inv);
        }
    }
}

// ---------------- launcher ----------------
extern "C" void kernel_launch(void* const* d_in, const int* in_sizes, int n_in,
                              void* d_out, int out_size, void* d_ws, size_t ws_size,
                              hipStream_t stream) {
    const float* x      = (const float*)d_in[0];
    const float* w_attn = (const float*)d_in[1];
    const float* b_attn = (const float*)d_in[2];
    const float* w_proj = (const float*)d_in[3];
    const float* b_proj = (const float*)d_in[4];
    float* out = (float*)d_out;

    char* ws = (char*)d_ws;
    unsigned short* q_ws  = (unsigned short*)(ws + 0);         // 8 MB [BH][T][HD]
    unsigned short* k_ws  = (unsigned short*)(ws + 8388608);   // 8 MB [BH][T][HD]
    unsigned short* vT_ws = (unsigned short*)(ws + 16777216);  // 8 MB [BH][HD][T]
    unsigned short* wtp   = (unsigned short*)(ws + 25165824);  // 2 MB [C][C]
    unsigned short* xb    = (unsigned short*)(ws + 27262976);  // 8 MB x as bf16
    unsigned short* y_ws  = (unsigned short*)(ws + 27262976);  // aliases xb (xb dead by then)
    unsigned short* wta   = (unsigned short*)(ws + 35651584);  // 6 MB [3C][C]

    // 1) fused prep: x->bf16 + both weight transposes
    k_prep<<<dim3(6144), 256, 0, stream>>>(x, w_attn, w_proj, xb, wta, wtp);

    // 2) QKV GEMM -> Q/K row-major + V^T   (grid 768, %8==0)
    k_gemm<1><<<dim3((N_QKV / 128) * (M_SZ / 128)), 256, 0, stream>>>(
        xb, wta, b_attn, nullptr, q_ws, k_ws, vT_ws, M_SZ, N_QKV, C_SZ, N_QKV / 128);

    // 3) causal flash attention -> y bf16 [B][T][C]
    k_attn<<<dim3(512), 256, 0, stream>>>(q_ws, k_ws, vT_ws, y_ws);

    // 4) proj GEMM: y @ w_proj + b_proj -> f32 out  (grid 256, %8==0)
    k_gemm<0><<<dim3((C_SZ / 128) * (M_SZ / 128)), 256, 0, stream>>>(
        y_ws, wtp, b_proj, out, nullptr, nullptr, nullptr, M_SZ, C_SZ, C_SZ, C_SZ / 128);
}

// Round 10
// 119.038 us; speedup vs baseline: 2.1930x; 1.0335x over previous
//
#include <hip/hip_runtime.h>
#include <hip/hip_bf16.h>
#include <stdint.h>

// Problem constants
#define B_SZ 2
#define T_SZ 2048
#define C_SZ 1024
#define H_SZ 16
#define HD   64
#define BH   (B_SZ * H_SZ)   // 32
#define M_SZ (B_SZ * T_SZ)   // 4096
#define N_QKV (3 * C_SZ)     // 3072

typedef __attribute__((ext_vector_type(8))) __bf16 bf16x8;
typedef __attribute__((ext_vector_type(4))) float f32x4;
typedef __attribute__((ext_vector_type(8))) unsigned short us8;
typedef __attribute__((ext_vector_type(4))) unsigned short us4;
typedef __attribute__((ext_vector_type(4))) unsigned int u32x4;

__device__ __forceinline__ unsigned short f2bf(float f) {
    unsigned int u = __builtin_bit_cast(unsigned int, f);
    u += 0x7fffu + ((u >> 16) & 1u);   // round-to-nearest-even
    return (unsigned short)(u >> 16);
}

// async global->LDS, 16B per lane; lds base must be wave-uniform (HW adds lane*16)
__device__ __forceinline__ void gll16(const unsigned short* g, unsigned short* l) {
    __builtin_amdgcn_global_load_lds(
        (const __attribute__((address_space(1))) unsigned int*)g,
        (__attribute__((address_space(3))) unsigned int*)l, 16, 0, 0);
}

// Barrier with EXPLICIT LDS-DMA drain (R7/R8 lesson: __syncthreads alone is not
// a reliable vmcnt(0) drain for in-flight global_load_lds in this structure).
__device__ __forceinline__ void hard_sync() {
    asm volatile("s_waitcnt vmcnt(0) lgkmcnt(0)" ::: "memory");
    __builtin_amdgcn_sched_barrier(0);
    __syncthreads();
}

// ---------------- prep: x->bf16 + both weight transposes (fused) ----------------
// grid: [0,2048) cvt x; [2048,5120) transpose w_attn; [5120,6144) transpose w_proj
__global__ __launch_bounds__(256) void k_prep(const float* __restrict__ x,
                                              const float* __restrict__ wa,
                                              const float* __restrict__ wp,
                                              unsigned short* __restrict__ xb,
                                              unsigned short* __restrict__ wta,
                                              unsigned short* __restrict__ wtp) {
    __shared__ float tile[32][33];
    const int tid = threadIdx.x;
    int idx = blockIdx.x;
    if (idx < 2048) {
        const size_t i = ((size_t)idx * 256 + tid) * 8;
        f32x4 a = *(const f32x4*)(x + i);
        f32x4 b = *(const f32x4*)(x + i + 4);
        us8 o;
        #pragma unroll
        for (int j = 0; j < 4; ++j) { o[j] = f2bf(a[j]); o[4 + j] = f2bf(b[j]); }
        *(us8*)(xb + i) = o;
        return;
    }
    const float* in; unsigned short* out; int N;
    if (idx < 5120) { idx -= 2048; in = wa; out = wta; N = N_QKV; }
    else            { idx -= 5120; in = wp; out = wtp; N = C_SZ; }
    const int nx = N / 32;
    const int n0 = (idx % nx) * 32, k0 = (idx / nx) * 32;
    const int tx = tid & 31, ty = tid >> 5;  // (32, 8)
    #pragma unroll
    for (int j = 0; j < 32; j += 8)
        tile[ty + j][tx] = in[(size_t)(k0 + ty + j) * N + (n0 + tx)];
    __syncthreads();
    #pragma unroll
    for (int j = 0; j < 32; j += 8)
        out[(size_t)(n0 + ty + j) * C_SZ + (k0 + tx)] = f2bf(tile[tx][ty + j]);
}

// ---------------- GEMM: C[M,N] = A[M,K](bf16) @ Bt[N,K]^T + bias ----------------
template <int EPI>
__global__ __launch_bounds__(256) void k_gemm(const unsigned short* __restrict__ A,
                                              const unsigned short* __restrict__ Bt,
                                              const float* __restrict__ bias,
                                              float* __restrict__ Cout,
                                              unsigned short* __restrict__ q_ws,
                                              unsigned short* __restrict__ k_ws,
                                              unsigned short* __restrict__ vT_ws,
                                              int M, int N, int K, int NX) {
    __shared__ __attribute__((aligned(16))) unsigned short Ald[128 * 64];
    __shared__ __attribute__((aligned(16))) unsigned short Bld[128 * 64];
    const int tid = threadIdx.x;
    const int wid = tid >> 6, lane = tid & 63;
    const int wr = wid >> 1, wc = wid & 1;
    const int g = lane >> 4, l15 = lane & 15;
    const int nwg = gridDim.x;
    const int wg = (blockIdx.x & 7) * (nwg >> 3) + (blockIdx.x >> 3);
    const int m0 = (wg / NX) * 128, n0 = (wg % NX) * 128;

    f32x4 acc[4][4];
    #pragma unroll
    for (int i = 0; i < 4; ++i)
        #pragma unroll
        for (int j = 0; j < 4; ++j) acc[i][j] = (f32x4){0.f, 0.f, 0.f, 0.f};

    for (int k0 = 0; k0 < K; k0 += 64) {
        hard_sync();
        #pragma unroll
        for (int i = 0; i < 4; ++i) {
            int c = i * 256 + tid;
            int row = c >> 3;
            int colb = ((c & 7) << 4) ^ ((row & 7) << 4);
            gll16(A  + (size_t)(m0 + row) * K + k0 + (colb >> 1), Ald + i * 2048 + wid * 512);
            gll16(Bt + (size_t)(n0 + row) * K + k0 + (colb >> 1), Bld + i * 2048 + wid * 512);
        }
        hard_sync();

        #pragma unroll
        for (int ks = 0; ks < 2; ++ks) {
            bf16x8 af[4], bfr[4];
            #pragma unroll
            for (int mi = 0; mi < 4; ++mi) {
                int row = wr * 64 + mi * 16 + l15;
                af[mi] = *(const bf16x8*)((const char*)Ald + row * 128 +
                                          ((ks * 64 + g * 16) ^ ((row & 7) << 4)));
            }
            #pragma unroll
            for (int nj = 0; nj < 4; ++nj) {
                int row = wc * 64 + nj * 16 + l15;
                bfr[nj] = *(const bf16x8*)((const char*)Bld + row * 128 +
                                           ((ks * 64 + g * 16) ^ ((row & 7) << 4)));
            }
            #pragma unroll
            for (int mi = 0; mi < 4; ++mi)
                #pragma unroll
                for (int nj = 0; nj < 4; ++nj)
                    acc[mi][nj] = __builtin_amdgcn_mfma_f32_16x16x32_bf16(
                        af[mi], bfr[nj], acc[mi][nj], 0, 0, 0);
        }
    }

    if (EPI == 0) {
        #pragma unroll
        for (int nj = 0; nj < 4; ++nj) {
            int col = n0 + wc * 64 + nj * 16 + l15;
            float bv = bias[col];
            #pragma unroll
            for (int mi = 0; mi < 4; ++mi) {
                int rowb = m0 + wr * 64 + mi * 16 + g * 4;
                #pragma unroll
                for (int r = 0; r < 4; ++r)
                    Cout[(size_t)(rowb + r) * N + col] = acc[mi][nj][r] + bv;
            }
        }
    } else {
        #pragma unroll
        for (int nj = 0; nj < 4; ++nj) {
            int col = n0 + wc * 64 + nj * 16 + l15;   // 0..3071
            float bv = bias[col];
            int which = col >> 10;
            int c10 = col & 1023;
            int h = c10 >> 6, d = c10 & 63;
            #pragma unroll
            for (int mi = 0; mi < 4; ++mi) {
                #pragma unroll
                for (int r = 0; r < 4; ++r) {
                    int row = m0 + wr * 64 + mi * 16 + g * 4 + r;  // 0..4095
                    int bb = row >> 11, t = row & 2047;
                    unsigned short val = f2bf(acc[mi][nj][r] + bv);
                    if (which == 2)
                        vT_ws[((size_t)(bb * H_SZ + h) * HD + d) * T_SZ + t] = val;       // V^T
                    else
                        (which ? k_ws : q_ws)[((size_t)(bb * H_SZ + h) * T_SZ + t) * HD + d] = val;
                }
            }
        }
    }
}

// ---------------- causal flash attention, KVBLK=128 ----------------
// 512 blocks: xcd=n&7, j=(n>>3)&15, rk=n>>7. bh = xcd + 8*rk (head-per-XCD L2
// clustering). Each block processes q-tile pair {31-j, j}; with 128-key steps
// each block runs EXACTLY 17 KV-steps (ceil((33-j)/2) + ceil((j+2)/2) = 17).
__global__ __launch_bounds__(256) void k_attn(const unsigned short* __restrict__ q_ws,
                                              const unsigned short* __restrict__ k_ws,
                                              const unsigned short* __restrict__ vT_ws,
                                              unsigned short* __restrict__ y_ws) {
    __shared__ __attribute__((aligned(16))) unsigned short Kbuf[2][8192];  // [128 keys][64 d]
    __shared__ __attribute__((aligned(16))) unsigned short Vbuf[2][8192];  // [64 d][128 t]
    const int tid = threadIdx.x;
    const int wid = tid >> 6, lane = tid & 63;
    const int g = lane >> 4, l15 = lane & 15;
    const int n = blockIdx.x;
    const int xcd = n & 7, j = (n >> 3) & 15, rk = n >> 7;
    const int bh = xcd + 8 * rk;
    const size_t kv_off = (size_t)bh * T_SZ * HD;
    const unsigned short* Kg = k_ws + kv_off;
    const unsigned short* Vg = vT_ws + (size_t)bh * HD * T_SZ;
    const int b = bh >> 4, h = bh & 15;
    const float SC = 0.125f * 1.44269504f;  // 1/sqrt(64) * log2(e)
    const int qloc = wid * 16 + l15;

    auto stageK = [&](int kv, int buf) {        // 128x64 bf16, swz (row&7)<<4
        #pragma unroll
        for (int i = 0; i < 4; ++i) {
            int c = i * 256 + tid;
            int row = c >> 3;
            int colb = ((c & 7) << 4) ^ ((row & 7) << 4);
            gll16(Kg + (size_t)(kv * 128 + row) * HD + (colb >> 1),
                  &Kbuf[buf][i * 2048 + wid * 512]);
        }
    };
    auto stageV = [&](int kv, int buf) {        // 64x128 bf16 (V^T), swz (row&15)<<4
        #pragma unroll
        for (int i = 0; i < 4; ++i) {
            int c = i * 256 + tid;
            int row = c >> 4;                              // d index
            int colb = ((c & 15) << 4) ^ ((row & 15) << 4); // t-offset bytes in 256B row
            gll16(Vg + (size_t)row * T_SZ + kv * 128 + (colb >> 1),
                  &Vbuf[buf][i * 2048 + wid * 512]);
        }
    };

    #pragma unroll 1
    for (int phase = 0; phase < 2; ++phase) {
        const int qb = phase ? j : (31 - j);
        const int nkv = (qb + 2) >> 1;          // ceil((qb*64+64)/128)

        // Q fragments for this phase
        const int qrow = qb * 64 + wid * 16 + l15;
        bf16x8 aq[2];
        aq[0] = *(const bf16x8*)(q_ws + kv_off + (size_t)qrow * HD + g * 8);
        aq[1] = *(const bf16x8*)(q_ws + kv_off + (size_t)qrow * HD + 32 + g * 8);

        float m_run = -3e38f, l_run = 0.f;
        f32x4 acc[4];
        #pragma unroll
        for (int dt = 0; dt < 4; ++dt) acc[dt] = (f32x4){0.f, 0.f, 0.f, 0.f};

        hard_sync();              // all waves done reading buffers (prev phase)
        stageK(0, 0); stageV(0, 0);
        int cur = 0;

        for (int kv = 0; kv < nkv; ++kv) {
            hard_sync();          // drain DMA: buf[cur] ready, buf[cur^1] free
            if (kv + 1 < nkv) { stageK(kv + 1, cur ^ 1); stageV(kv + 1, cur ^ 1); }
            const char* Kb = (const char*)Kbuf[cur];
            const char* Vb = (const char*)Vbuf[cur];

            // S^T = K @ Q^T : lane holds keys kt*16+4g+r (kt=0..7) for q=l15
            f32x4 st[8];
            __builtin_amdgcn_s_setprio(1);
            #pragma unroll
            for (int kt = 0; kt < 8; ++kt) {
                f32x4 sv = (f32x4){0.f, 0.f, 0.f, 0.f};
                #pragma unroll
                for (int ks = 0; ks < 2; ++ks) {
                    int row = kt * 16 + l15;
                    bf16x8 ak = *(const bf16x8*)(Kb + row * 128 +
                                                 ((ks * 64 + g * 16) ^ ((row & 7) << 4)));
                    sv = __builtin_amdgcn_mfma_f32_16x16x32_bf16(ak, aq[ks], sv, 0, 0, 0);
                }
                st[kt] = sv;
            }
            __builtin_amdgcn_s_setprio(0);

            // raw (unscaled) S with causal mask on the last (diagonal) step
            float t[32];
            #pragma unroll
            for (int kt = 0; kt < 8; ++kt)
                #pragma unroll
                for (int r = 0; r < 4; ++r) t[kt * 4 + r] = st[kt][r];
            if (kv == nkv - 1) {
                const int off = kv * 128 - qb * 64;   // key-global minus q-tile base
                #pragma unroll
                for (int kt = 0; kt < 8; ++kt)
                    #pragma unroll
                    for (int r = 0; r < 4; ++r)
                        if (kt * 16 + g * 4 + r + off > qloc) t[kt * 4 + r] = -3e38f;
            }

            // tile max: tree over 32 + 2 shfl cross-lane, single scale mult
            float m16[16];
            #pragma unroll
            for (int i = 0; i < 16; ++i) m16[i] = fmaxf(t[i], t[i + 16]);
            float m8[8];
            #pragma unroll
            for (int i = 0; i < 8; ++i) m8[i] = fmaxf(m16[i], m16[i + 8]);
            float m4[4];
            #pragma unroll
            for (int i = 0; i < 4; ++i) m4[i] = fmaxf(m8[i], m8[i + 4]);
            float mx = fmaxf(fmaxf(m4[0], m4[1]), fmaxf(m4[2], m4[3]));
            mx = fmaxf(mx, __shfl_xor(mx, 16, 64));
            mx = fmaxf(mx, __shfl_xor(mx, 32, 64));
            float mt = mx * SC;

            // defer-max (T13): only rescale when the tile max grew past THR=8
            if (!__all(mt - m_run <= 8.0f)) {
                float mnew = fmaxf(m_run, mt);
                float alpha = exp2f(m_run - mnew);
                m_run = mnew;
                l_run *= alpha;
                float ao[4];
                #pragma unroll
                for (int r = 0; r < 4; ++r) {
                    int ai = __builtin_amdgcn_ds_bpermute((g * 4 + r) * 4,
                                                          __builtin_bit_cast(int, alpha));
                    ao[r] = __builtin_bit_cast(float, ai);
                }
                #pragma unroll
                for (int dt = 0; dt < 4; ++dt)
                    #pragma unroll
                    for (int r = 0; r < 4; ++r) acc[dt][r] *= ao[r];
            }

            // p = exp2(S*SC - m) via fma; tree-sum + 2 shfl
            float p[32];
            #pragma unroll
            for (int i = 0; i < 32; ++i) p[i] = exp2f(fmaf(t[i], SC, -m_run));
            float s16[16];
            #pragma unroll
            for (int i = 0; i < 16; ++i) s16[i] = p[i] + p[i + 16];
            float s8[8];
            #pragma unroll
            for (int i = 0; i < 8; ++i) s8[i] = s16[i] + s16[i + 8];
            float s4[4];
            #pragma unroll
            for (int i = 0; i < 4; ++i) s4[i] = s8[i] + s8[i + 4];
            float sum = (s4[0] + s4[1]) + (s4[2] + s4[3]);
            sum += __shfl_xor(sum, 16, 64);
            sum += __shfl_xor(sum, 32, 64);
            l_run += sum;

            // P -> bf16 pairs, then permlane swaps rebuild A-fragments per ks
            unsigned int pk0[8], pk1[8];
            #pragma unroll
            for (int kt = 0; kt < 8; ++kt) {
                asm("v_cvt_pk_bf16_f32 %0, %1, %2" : "=v"(pk0[kt]) : "v"(p[kt * 4 + 0]), "v"(p[kt * 4 + 1]));
                asm("v_cvt_pk_bf16_f32 %0, %1, %2" : "=v"(pk1[kt]) : "v"(p[kt * 4 + 2]), "v"(p[kt * 4 + 3]));
            }
            __builtin_amdgcn_s_setprio(1);
            #pragma unroll
            for (int ks = 0; ks < 4; ++ks) {
                unsigned int x0 = pk0[2 * ks], y0 = pk0[2 * ks + 1];
                unsigned int x1 = pk1[2 * ks], y1 = pk1[2 * ks + 1];
                asm("v_permlane32_swap_b32 %0, %1" : "+v"(x0), "+v"(y0));
                asm("v_permlane16_swap_b32 %0, %1" : "+v"(x0), "+v"(y0));
                asm("v_permlane32_swap_b32 %0, %1" : "+v"(x1), "+v"(y1));
                asm("v_permlane16_swap_b32 %0, %1" : "+v"(x1), "+v"(y1));
                bf16x8 ap = __builtin_bit_cast(bf16x8, (u32x4){x0, x1, y0, y1});
                #pragma unroll
                for (int dt = 0; dt < 4; ++dt) {
                    int row = dt * 16 + l15;
                    bf16x8 bv = *(const bf16x8*)(Vb + row * 256 +
                                                 ((ks * 64 + g * 16) ^ ((row & 15) << 4)));
                    acc[dt] = __builtin_amdgcn_mfma_f32_16x16x32_bf16(ap, bv, acc[dt], 0, 0, 0);
                }
            }
            __builtin_amdgcn_s_setprio(0);
            cur ^= 1;
        }

        // epilogue: gather l for q=4g+r, normalize, store y[b,t,h*64+d]
        float lo[4];
        #pragma unroll
        for (int r = 0; r < 4; ++r) {
            int li = __builtin_amdgcn_ds_bpermute((g * 4 + r) * 4,
                                                  __builtin_bit_cast(int, l_run));
            lo[r] = __builtin_bit_cast(float, li);
        }
        #pragma unroll
        for (int r = 0; r < 4; ++r) {
            int tq = qb * 64 + wid * 16 + g * 4 + r;
            float inv = 1.0f / lo[r];
            #pragma unroll
            for (int dt = 0; dt < 4; ++dt)
                y_ws[(size_t)(b * T_SZ + tq) * C_SZ + h * 64 + dt * 16 + l15] =
                    f2bf(acc[dt][r] * inv);
        }
    }
}

// ---------------- launcher ----------------
extern "C" void kernel_launch(void* const* d_in, const int* in_sizes, int n_in,
                              void* d_out, int out_size, void* d_ws, size_t ws_size,
                              hipStream_t stream) {
    const float* x      = (const float*)d_in[0];
    const float* w_attn = (const float*)d_in[1];
    const float* b_attn = (const float*)d_in[2];
    const float* w_proj = (const float*)d_in[3];
    const float* b_proj = (const float*)d_in[4];
    float* out = (float*)d_out;

    char* ws = (char*)d_ws;
    unsigned short* q_ws  = (unsigned short*)(ws + 0);         // 8 MB [BH][T][HD]
    unsigned short* k_ws  = (unsigned short*)(ws + 8388608);   // 8 MB [BH][T][HD]
    unsigned short* vT_ws = (unsigned short*)(ws + 16777216);  // 8 MB [BH][HD][T]
    unsigned short* wtp   = (unsigned short*)(ws + 25165824);  // 2 MB [C][C]
    unsigned short* xb    = (unsigned short*)(ws + 27262976);  // 8 MB x as bf16
    unsigned short* y_ws  = (unsigned short*)(ws + 27262976);  // aliases xb (xb dead by then)
    unsigned short* wta   = (unsigned short*)(ws + 35651584);  // 6 MB [3C][C]

    // 1) fused prep: x->bf16 + both weight transposes
    k_prep<<<dim3(6144), 256, 0, stream>>>(x, w_attn, w_proj, xb, wta, wtp);

    // 2) QKV GEMM -> Q/K row-major + V^T   (grid 768, %8==0)
    k_gemm<1><<<dim3((N_QKV / 128) * (M_SZ / 128)), 256, 0, stream>>>(
        xb, wta, b_attn, nullptr, q_ws, k_ws, vT_ws, M_SZ, N_QKV, C_SZ, N_QKV / 128);

    // 3) causal flash attention -> y bf16 [B][T][C]
    k_attn<<<dim3(512), 256, 0, stream>>>(q_ws, k_ws, vT_ws, y_ws);

    // 4) proj GEMM: y @ w_proj + b_proj -> f32 out  (grid 256, %8==0)
    k_gemm<0><<<dim3((C_SZ / 128) * (M_SZ / 128)), 256, 0, stream>>>(
        y_ws, wtp, b_proj, out, nullptr, nullptr, nullptr, M_SZ, C_SZ, C_SZ, C_SZ / 128);
}

// Round 11
// 118.088 us; speedup vs baseline: 2.2107x; 1.0081x over previous
//
#include <hip/hip_runtime.h>
#include <hip/hip_bf16.h>
#include <stdint.h>

// Problem constants
#define B_SZ 2
#define T_SZ 2048
#define C_SZ 1024
#define H_SZ 16
#define HD   64
#define BH   (B_SZ * H_SZ)   // 32
#define M_SZ (B_SZ * T_SZ)   // 4096
#define N_QKV (3 * C_SZ)     // 3072

typedef __attribute__((ext_vector_type(8))) __bf16 bf16x8;
typedef __attribute__((ext_vector_type(4))) float f32x4;
typedef __attribute__((ext_vector_type(8))) unsigned short us8;
typedef __attribute__((ext_vector_type(4))) unsigned short us4;
typedef __attribute__((ext_vector_type(4))) unsigned int u32x4;

__device__ __forceinline__ unsigned short f2bf(float f) {
    unsigned int u = __builtin_bit_cast(unsigned int, f);
    u += 0x7fffu + ((u >> 16) & 1u);   // round-to-nearest-even
    return (unsigned short)(u >> 16);
}

// async global->LDS, 16B per lane; lds base must be wave-uniform (HW adds lane*16)
__device__ __forceinline__ void gll16(const unsigned short* g, unsigned short* l) {
    __builtin_amdgcn_global_load_lds(
        (const __attribute__((address_space(1))) unsigned int*)g,
        (__attribute__((address_space(3))) unsigned int*)l, 16, 0, 0);
}

// Barrier with EXPLICIT LDS-DMA drain (R7/R8 lesson: __syncthreads alone is not
// a reliable vmcnt(0) drain for in-flight global_load_lds in this structure).
__device__ __forceinline__ void hard_sync() {
    asm volatile("s_waitcnt vmcnt(0) lgkmcnt(0)" ::: "memory");
    __builtin_amdgcn_sched_barrier(0);
    __syncthreads();
}

// ---------------- prep: x->bf16 + both weight transposes (fused) ----------------
// grid: [0,2048) cvt x; [2048,5120) transpose w_attn; [5120,6144) transpose w_proj
__global__ __launch_bounds__(256) void k_prep(const float* __restrict__ x,
                                              const float* __restrict__ wa,
                                              const float* __restrict__ wp,
                                              unsigned short* __restrict__ xb,
                                              unsigned short* __restrict__ wta,
                                              unsigned short* __restrict__ wtp) {
    __shared__ float tile[32][33];
    const int tid = threadIdx.x;
    int idx = blockIdx.x;
    if (idx < 2048) {
        const size_t i = ((size_t)idx * 256 + tid) * 8;
        f32x4 a = *(const f32x4*)(x + i);
        f32x4 b = *(const f32x4*)(x + i + 4);
        us8 o;
        #pragma unroll
        for (int j = 0; j < 4; ++j) { o[j] = f2bf(a[j]); o[4 + j] = f2bf(b[j]); }
        *(us8*)(xb + i) = o;
        return;
    }
    const float* in; unsigned short* out; int N;
    if (idx < 5120) { idx -= 2048; in = wa; out = wta; N = N_QKV; }
    else            { idx -= 5120; in = wp; out = wtp; N = C_SZ; }
    const int nx = N / 32;
    const int n0 = (idx % nx) * 32, k0 = (idx / nx) * 32;
    const int tx = tid & 31, ty = tid >> 5;  // (32, 8)
    #pragma unroll
    for (int j = 0; j < 32; j += 8)
        tile[ty + j][tx] = in[(size_t)(k0 + ty + j) * N + (n0 + tx)];
    __syncthreads();
    #pragma unroll
    for (int j = 0; j < 32; j += 8)
        out[(size_t)(n0 + ty + j) * C_SZ + (k0 + tx)] = f2bf(tile[tx][ty + j]);
}

// ---------------- GEMM: C[M,N] = A[M,K](bf16) @ Bt[N,K]^T + bias ----------------
template <int EPI>
__global__ __launch_bounds__(256) void k_gemm(const unsigned short* __restrict__ A,
                                              const unsigned short* __restrict__ Bt,
                                              const float* __restrict__ bias,
                                              float* __restrict__ Cout,
                                              unsigned short* __restrict__ q_ws,
                                              unsigned short* __restrict__ k_ws,
                                              unsigned short* __restrict__ vT_ws,
                                              int M, int N, int K, int NX) {
    __shared__ __attribute__((aligned(16))) unsigned short Ald[128 * 64];
    __shared__ __attribute__((aligned(16))) unsigned short Bld[128 * 64];
    const int tid = threadIdx.x;
    const int wid = tid >> 6, lane = tid & 63;
    const int wr = wid >> 1, wc = wid & 1;
    const int g = lane >> 4, l15 = lane & 15;
    const int nwg = gridDim.x;
    const int wg = (blockIdx.x & 7) * (nwg >> 3) + (blockIdx.x >> 3);
    const int m0 = (wg / NX) * 128, n0 = (wg % NX) * 128;

    f32x4 acc[4][4];
    #pragma unroll
    for (int i = 0; i < 4; ++i)
        #pragma unroll
        for (int j = 0; j < 4; ++j) acc[i][j] = (f32x4){0.f, 0.f, 0.f, 0.f};

    for (int k0 = 0; k0 < K; k0 += 64) {
        hard_sync();
        #pragma unroll
        for (int i = 0; i < 4; ++i) {
            int c = i * 256 + tid;
            int row = c >> 3;
            int colb = ((c & 7) << 4) ^ ((row & 7) << 4);
            gll16(A  + (size_t)(m0 + row) * K + k0 + (colb >> 1), Ald + i * 2048 + wid * 512);
            gll16(Bt + (size_t)(n0 + row) * K + k0 + (colb >> 1), Bld + i * 2048 + wid * 512);
        }
        hard_sync();

        #pragma unroll
        for (int ks = 0; ks < 2; ++ks) {
            bf16x8 af[4], bfr[4];
            #pragma unroll
            for (int mi = 0; mi < 4; ++mi) {
                int row = wr * 64 + mi * 16 + l15;
                af[mi] = *(const bf16x8*)((const char*)Ald + row * 128 +
                                          ((ks * 64 + g * 16) ^ ((row & 7) << 4)));
            }
            #pragma unroll
            for (int nj = 0; nj < 4; ++nj) {
                int row = wc * 64 + nj * 16 + l15;
                bfr[nj] = *(const bf16x8*)((const char*)Bld + row * 128 +
                                           ((ks * 64 + g * 16) ^ ((row & 7) << 4)));
            }
            #pragma unroll
            for (int mi = 0; mi < 4; ++mi)
                #pragma unroll
                for (int nj = 0; nj < 4; ++nj)
                    acc[mi][nj] = __builtin_amdgcn_mfma_f32_16x16x32_bf16(
                        af[mi], bfr[nj], acc[mi][nj], 0, 0, 0);
        }
    }

    if (EPI == 0) {
        #pragma unroll
        for (int nj = 0; nj < 4; ++nj) {
            int col = n0 + wc * 64 + nj * 16 + l15;
            float bv = bias[col];
            #pragma unroll
            for (int mi = 0; mi < 4; ++mi) {
                int rowb = m0 + wr * 64 + mi * 16 + g * 4;
                #pragma unroll
                for (int r = 0; r < 4; ++r)
                    Cout[(size_t)(rowb + r) * N + col] = acc[mi][nj][r] + bv;
            }
        }
    } else {
        #pragma unroll
        for (int nj = 0; nj < 4; ++nj) {
            int col = n0 + wc * 64 + nj * 16 + l15;   // 0..3071
            float bv = bias[col];
            int which = col >> 10;
            int c10 = col & 1023;
            int h = c10 >> 6, d = c10 & 63;
            #pragma unroll
            for (int mi = 0; mi < 4; ++mi) {
                #pragma unroll
                for (int r = 0; r < 4; ++r) {
                    int row = m0 + wr * 64 + mi * 16 + g * 4 + r;  // 0..4095
                    int bb = row >> 11, t = row & 2047;
                    unsigned short val = f2bf(acc[mi][nj][r] + bv);
                    if (which == 2)
                        vT_ws[((size_t)(bb * H_SZ + h) * HD + d) * T_SZ + t] = val;       // V^T
                    else
                        (which ? k_ws : q_ws)[((size_t)(bb * H_SZ + h) * T_SZ + t) * HD + d] = val;
                }
            }
        }
    }
}

// ---------------- causal flash attention, QBLK=128 / KVBLK=128 / 512 thr ----------------
// 256 blocks (1/CU): xcd=n&7, j=(n>>3)&7 (pair), rk=n>>6. bh = xcd + 8*rk.
// Each block: 8 waves x 16 q-rows = 128 q-rows per phase; phases {15-j, j}
// (128-row q-tiles) -> exactly 17 KV-steps per block. Diagonal tile is
// square-aligned: causal mask is key_local > q_local (no offset).
__global__ __launch_bounds__(512) void k_attn(const unsigned short* __restrict__ q_ws,
                                              const unsigned short* __restrict__ k_ws,
                                              const unsigned short* __restrict__ vT_ws,
                                              unsigned short* __restrict__ y_ws) {
    __shared__ __attribute__((aligned(16))) unsigned short Kbuf[2][8192];  // [128 keys][64 d]
    __shared__ __attribute__((aligned(16))) unsigned short Vbuf[2][8192];  // [64 d][128 t]
    const int tid = threadIdx.x;
    const int wid = tid >> 6, lane = tid & 63;
    const int g = lane >> 4, l15 = lane & 15;
    const int n = blockIdx.x;
    const int xcd = n & 7, j = (n >> 3) & 7, rk = n >> 6;
    const int bh = xcd + 8 * rk;
    const size_t kv_off = (size_t)bh * T_SZ * HD;
    const unsigned short* Kg = k_ws + kv_off;
    const unsigned short* Vg = vT_ws + (size_t)bh * HD * T_SZ;
    const int b = bh >> 4, h = bh & 15;
    const float SC = 0.125f * 1.44269504f;  // 1/sqrt(64) * log2(e)
    const int qloc = wid * 16 + l15;        // q-row within 128-row tile... (see mask: uses l15 lane->q)

    auto stageK = [&](int kv, int buf) {        // 128x64 bf16, swz (row&7)<<4
        #pragma unroll
        for (int i = 0; i < 2; ++i) {
            int c = i * 512 + tid;
            int row = c >> 3;
            int colb = ((c & 7) << 4) ^ ((row & 7) << 4);
            gll16(Kg + (size_t)(kv * 128 + row) * HD + (colb >> 1),
                  &Kbuf[buf][i * 4096 + wid * 512]);
        }
    };
    auto stageV = [&](int kv, int buf) {        // 64x128 bf16 (V^T), swz (row&15)<<4
        #pragma unroll
        for (int i = 0; i < 2; ++i) {
            int c = i * 512 + tid;
            int row = c >> 4;                               // d index
            int colb = ((c & 15) << 4) ^ ((row & 15) << 4); // t-offset bytes in 256B row
            gll16(Vg + (size_t)row * T_SZ + kv * 128 + (colb >> 1),
                  &Vbuf[buf][i * 4096 + wid * 512]);
        }
    };

    #pragma unroll 1
    for (int phase = 0; phase < 2; ++phase) {
        const int qt = phase ? j : (15 - j);    // 128-row q-tile index
        const int nkv = qt + 1;                 // KV steps (128 keys each)

        // Q fragments for this phase (wave's 16 q rows; q = l15 within fragment)
        const int qrow = qt * 128 + wid * 16 + l15;
        bf16x8 aq[2];
        aq[0] = *(const bf16x8*)(q_ws + kv_off + (size_t)qrow * HD + g * 8);
        aq[1] = *(const bf16x8*)(q_ws + kv_off + (size_t)qrow * HD + 32 + g * 8);

        float m_run = -3e38f, l_part = 0.f;     // l_part: per-lane partial (reduced at epilogue)
        f32x4 acc[4];
        #pragma unroll
        for (int dt = 0; dt < 4; ++dt) acc[dt] = (f32x4){0.f, 0.f, 0.f, 0.f};

        hard_sync();              // all waves done reading buffers (prev phase)
        stageK(0, 0); stageV(0, 0);
        int cur = 0;

        for (int kv = 0; kv < nkv; ++kv) {
            hard_sync();          // drain DMA: buf[cur] ready, buf[cur^1] free
            if (kv + 1 < nkv) { stageK(kv + 1, cur ^ 1); stageV(kv + 1, cur ^ 1); }
            const char* Kb = (const char*)Kbuf[cur];
            const char* Vb = (const char*)Vbuf[cur];

            // S^T = K @ Q^T : lane holds keys kt*16+4g+r (kt=0..7) for q=l15
            f32x4 st[8];
            __builtin_amdgcn_s_setprio(1);
            #pragma unroll
            for (int kt = 0; kt < 8; ++kt) {
                f32x4 sv = (f32x4){0.f, 0.f, 0.f, 0.f};
                #pragma unroll
                for (int ks = 0; ks < 2; ++ks) {
                    int row = kt * 16 + l15;
                    bf16x8 ak = *(const bf16x8*)(Kb + row * 128 +
                                                 ((ks * 64 + g * 16) ^ ((row & 7) << 4)));
                    sv = __builtin_amdgcn_mfma_f32_16x16x32_bf16(ak, aq[ks], sv, 0, 0, 0);
                }
                st[kt] = sv;
            }
            __builtin_amdgcn_s_setprio(0);

            // raw (unscaled) S with causal mask on the last (diagonal) step.
            // Diagonal tile square-aligned: key_local kt*16+g*4+r vs q_local l15-row
            float t[32];
            #pragma unroll
            for (int kt = 0; kt < 8; ++kt)
                #pragma unroll
                for (int r = 0; r < 4; ++r) t[kt * 4 + r] = st[kt][r];
            if (kv == nkv - 1) {
                const int ql = wid * 16 + l15;  // q within 128-row tile? No: q = l15 of THIS wave's 16 rows
                #pragma unroll
                for (int kt = 0; kt < 8; ++kt)
                    #pragma unroll
                    for (int r = 0; r < 4; ++r)
                        if (kt * 16 + g * 4 + r > ql) t[kt * 4 + r] = -3e38f;
            }

            // tile max: tree over 32 + 2 shfl cross-lane (per-q group), scale once
            float m16[16];
            #pragma unroll
            for (int i = 0; i < 16; ++i) m16[i] = fmaxf(t[i], t[i + 16]);
            float m8v[8];
            #pragma unroll
            for (int i = 0; i < 8; ++i) m8v[i] = fmaxf(m16[i], m16[i + 8]);
            float m4v[4];
            #pragma unroll
            for (int i = 0; i < 4; ++i) m4v[i] = fmaxf(m8v[i], m8v[i + 4]);
            float mx = fmaxf(fmaxf(m4v[0], m4v[1]), fmaxf(m4v[2], m4v[3]));
            mx = fmaxf(mx, __shfl_xor(mx, 16, 64));
            mx = fmaxf(mx, __shfl_xor(mx, 32, 64));
            float mt = mx * SC;

            // defer-max (T13): only rescale when the tile max grew past THR=8
            if (!__all(mt - m_run <= 8.0f)) {
                float mnew = fmaxf(m_run, mt);
                float alpha = exp2f(m_run - mnew);   // uniform within 4-lane q-group
                m_run = mnew;
                l_part *= alpha;
                float ao[4];
                #pragma unroll
                for (int r = 0; r < 4; ++r) {
                    int ai = __builtin_amdgcn_ds_bpermute((g * 4 + r) * 4,
                                                          __builtin_bit_cast(int, alpha));
                    ao[r] = __builtin_bit_cast(float, ai);
                }
                #pragma unroll
                for (int dt = 0; dt < 4; ++dt)
                    #pragma unroll
                    for (int r = 0; r < 4; ++r) acc[dt][r] *= ao[r];
            }

            // p = exp2(S*SC - m) via fma; per-lane partial sum only (no shfl here)
            float p[32];
            #pragma unroll
            for (int i = 0; i < 32; ++i) p[i] = exp2f(fmaf(t[i], SC, -m_run));
            float s16[16];
            #pragma unroll
            for (int i = 0; i < 16; ++i) s16[i] = p[i] + p[i + 16];
            float s8v[8];
            #pragma unroll
            for (int i = 0; i < 8; ++i) s8v[i] = s16[i] + s16[i + 8];
            float s4v[4];
            #pragma unroll
            for (int i = 0; i < 4; ++i) s4v[i] = s8v[i] + s8v[i + 4];
            l_part += (s4v[0] + s4v[1]) + (s4v[2] + s4v[3]);

            // P -> bf16 pairs, then permlane swaps rebuild A-fragments per ks
            unsigned int pk0[8], pk1[8];
            #pragma unroll
            for (int kt = 0; kt < 8; ++kt) {
                asm("v_cvt_pk_bf16_f32 %0, %1, %2" : "=v"(pk0[kt]) : "v"(p[kt * 4 + 0]), "v"(p[kt * 4 + 1]));
                asm("v_cvt_pk_bf16_f32 %0, %1, %2" : "=v"(pk1[kt]) : "v"(p[kt * 4 + 2]), "v"(p[kt * 4 + 3]));
            }
            __builtin_amdgcn_s_setprio(1);
            #pragma unroll
            for (int ks = 0; ks < 4; ++ks) {
                unsigned int x0 = pk0[2 * ks], y0 = pk0[2 * ks + 1];
                unsigned int x1 = pk1[2 * ks], y1 = pk1[2 * ks + 1];
                asm("v_permlane32_swap_b32 %0, %1" : "+v"(x0), "+v"(y0));
                asm("v_permlane16_swap_b32 %0, %1" : "+v"(x0), "+v"(y0));
                asm("v_permlane32_swap_b32 %0, %1" : "+v"(x1), "+v"(y1));
                asm("v_permlane16_swap_b32 %0, %1" : "+v"(x1), "+v"(y1));
                bf16x8 ap = __builtin_bit_cast(bf16x8, (u32x4){x0, x1, y0, y1});
                #pragma unroll
                for (int dt = 0; dt < 4; ++dt) {
                    int row = dt * 16 + l15;
                    bf16x8 bv = *(const bf16x8*)(Vb + row * 256 +
                                                 ((ks * 64 + g * 16) ^ ((row & 15) << 4)));
                    acc[dt] = __builtin_amdgcn_mfma_f32_16x16x32_bf16(ap, bv, acc[dt], 0, 0, 0);
                }
            }
            __builtin_amdgcn_s_setprio(0);
            cur ^= 1;
        }

        // epilogue: reduce l across the 4-lane q-group, gather for q=4g+r, store
        float lsum = l_part;
        lsum += __shfl_xor(lsum, 16, 64);
        lsum += __shfl_xor(lsum, 32, 64);
        float lo[4];
        #pragma unroll
        for (int r = 0; r < 4; ++r) {
            int li = __builtin_amdgcn_ds_bpermute((g * 4 + r) * 4,
                                                  __builtin_bit_cast(int, lsum));
            lo[r] = __builtin_bit_cast(float, li);
        }
        #pragma unroll
        for (int r = 0; r < 4; ++r) {
            int tq = qt * 128 + wid * 16 + g * 4 + r;
            float inv = 1.0f / lo[r];
            #pragma unroll
            for (int dt = 0; dt < 4; ++dt)
                y_ws[(size_t)(b * T_SZ + tq) * C_SZ + h * 64 + dt * 16 + l15] =
                    f2bf(acc[dt][r] * inv);
        }
    }
}

// ---------------- launcher ----------------
extern "C" void kernel_launch(void* const* d_in, const int* in_sizes, int n_in,
                              void* d_out, int out_size, void* d_ws, size_t ws_size,
                              hipStream_t stream) {
    const float* x      = (const float*)d_in[0];
    const float* w_attn = (const float*)d_in[1];
    const float* b_attn = (const float*)d_in[2];
    const float* w_proj = (const float*)d_in[3];
    const float* b_proj = (const float*)d_in[4];
    float* out = (float*)d_out;

    char* ws = (char*)d_ws;
    unsigned short* q_ws  = (unsigned short*)(ws + 0);         // 8 MB [BH][T][HD]
    unsigned short* k_ws  = (unsigned short*)(ws + 8388608);   // 8 MB [BH][T][HD]
    unsigned short* vT_ws = (unsigned short*)(ws + 16777216);  // 8 MB [BH][HD][T]
    unsigned short* wtp   = (unsigned short*)(ws + 25165824);  // 2 MB [C][C]
    unsigned short* xb    = (unsigned short*)(ws + 27262976);  // 8 MB x as bf16
    unsigned short* y_ws  = (unsigned short*)(ws + 27262976);  // aliases xb (xb dead by then)
    unsigned short* wta   = (unsigned short*)(ws + 35651584);  // 6 MB [3C][C]

    // 1) fused prep: x->bf16 + both weight transposes
    k_prep<<<dim3(6144), 256, 0, stream>>>(x, w_attn, w_proj, xb, wta, wtp);

    // 2) QKV GEMM -> Q/K row-major + V^T   (grid 768, %8==0)
    k_gemm<1><<<dim3((N_QKV / 128) * (M_SZ / 128)), 256, 0, stream>>>(
        xb, wta, b_attn, nullptr, q_ws, k_ws, vT_ws, M_SZ, N_QKV, C_SZ, N_QKV / 128);

    // 3) causal flash attention -> y bf16 [B][T][C]  (256 blocks x 512 thr)
    k_attn<<<dim3(256), 512, 0, stream>>>(q_ws, k_ws, vT_ws, y_ws);

    // 4) proj GEMM: y @ w_proj + b_proj -> f32 out  (grid 256, %8==0)
    k_gemm<0><<<dim3((C_SZ / 128) * (M_SZ / 128)), 256, 0, stream>>>(
        y_ws, wtp, b_proj, out, nullptr, nullptr, nullptr, M_SZ, C_SZ, C_SZ, C_SZ / 128);
}

// Round 12
// 114.007 us; speedup vs baseline: 2.2898x; 1.0358x over previous
//
#include <hip/hip_runtime.h>
#include <hip/hip_bf16.h>
#include <stdint.h>

// Problem constants
#define B_SZ 2
#define T_SZ 2048
#define C_SZ 1024
#define H_SZ 16
#define HD   64
#define BH   (B_SZ * H_SZ)   // 32
#define M_SZ (B_SZ * T_SZ)   // 4096
#define N_QKV (3 * C_SZ)     // 3072

typedef __attribute__((ext_vector_type(8))) __bf16 bf16x8;
typedef __attribute__((ext_vector_type(4))) float f32x4;
typedef __attribute__((ext_vector_type(8))) unsigned short us8;
typedef __attribute__((ext_vector_type(4))) unsigned short us4;
typedef __attribute__((ext_vector_type(4))) unsigned int u32x4;

__device__ __forceinline__ unsigned short f2bf(float f) {
    unsigned int u = __builtin_bit_cast(unsigned int, f);
    u += 0x7fffu + ((u >> 16) & 1u);   // round-to-nearest-even
    return (unsigned short)(u >> 16);
}

// async global->LDS, 16B per lane; lds base must be wave-uniform (HW adds lane*16)
__device__ __forceinline__ void gll16(const unsigned short* g, unsigned short* l) {
    __builtin_amdgcn_global_load_lds(
        (const __attribute__((address_space(1))) unsigned int*)g,
        (__attribute__((address_space(3))) unsigned int*)l, 16, 0, 0);
}

// Barrier with EXPLICIT LDS-DMA drain (R7/R8 lesson: __syncthreads alone is not
// a reliable vmcnt(0) drain for in-flight global_load_lds in this structure).
__device__ __forceinline__ void hard_sync() {
    asm volatile("s_waitcnt vmcnt(0) lgkmcnt(0)" ::: "memory");
    __builtin_amdgcn_sched_barrier(0);
    __syncthreads();
}

// ---------------- prep: x->bf16 + both weight transposes (fused) ----------------
// grid: [0,2048) cvt x; [2048,5120) transpose w_attn; [5120,6144) transpose w_proj
__global__ __launch_bounds__(256) void k_prep(const float* __restrict__ x,
                                              const float* __restrict__ wa,
                                              const float* __restrict__ wp,
                                              unsigned short* __restrict__ xb,
                                              unsigned short* __restrict__ wta,
                                              unsigned short* __restrict__ wtp) {
    __shared__ float tile[32][33];
    const int tid = threadIdx.x;
    int idx = blockIdx.x;
    if (idx < 2048) {
        const size_t i = ((size_t)idx * 256 + tid) * 8;
        f32x4 a = *(const f32x4*)(x + i);
        f32x4 b = *(const f32x4*)(x + i + 4);
        us8 o;
        #pragma unroll
        for (int j = 0; j < 4; ++j) { o[j] = f2bf(a[j]); o[4 + j] = f2bf(b[j]); }
        *(us8*)(xb + i) = o;
        return;
    }
    const float* in; unsigned short* out; int N;
    if (idx < 5120) { idx -= 2048; in = wa; out = wta; N = N_QKV; }
    else            { idx -= 5120; in = wp; out = wtp; N = C_SZ; }
    const int nx = N / 32;
    const int n0 = (idx % nx) * 32, k0 = (idx / nx) * 32;
    const int tx = tid & 31, ty = tid >> 5;  // (32, 8)
    #pragma unroll
    for (int j = 0; j < 32; j += 8)
        tile[ty + j][tx] = in[(size_t)(k0 + ty + j) * N + (n0 + tx)];
    __syncthreads();
    #pragma unroll
    for (int j = 0; j < 32; j += 8)
        out[(size_t)(n0 + ty + j) * C_SZ + (k0 + tx)] = f2bf(tile[tx][ty + j]);
}

// ---------------- GEMM: C[M,N] = A[M,K](bf16) @ Bt[N,K]^T + bias ----------------
template <int EPI>
__global__ __launch_bounds__(256) void k_gemm(const unsigned short* __restrict__ A,
                                              const unsigned short* __restrict__ Bt,
                                              const float* __restrict__ bias,
                                              float* __restrict__ Cout,
                                              unsigned short* __restrict__ q_ws,
                                              unsigned short* __restrict__ k_ws,
                                              unsigned short* __restrict__ vT_ws,
                                              int M, int N, int K, int NX) {
    __shared__ __attribute__((aligned(16))) unsigned short Ald[128 * 64];
    __shared__ __attribute__((aligned(16))) unsigned short Bld[128 * 64];
    const int tid = threadIdx.x;
    const int wid = tid >> 6, lane = tid & 63;
    const int wr = wid >> 1, wc = wid & 1;
    const int g = lane >> 4, l15 = lane & 15;
    const int nwg = gridDim.x;
    const int wg = (blockIdx.x & 7) * (nwg >> 3) + (blockIdx.x >> 3);
    const int m0 = (wg / NX) * 128, n0 = (wg % NX) * 128;

    f32x4 acc[4][4];
    #pragma unroll
    for (int i = 0; i < 4; ++i)
        #pragma unroll
        for (int j = 0; j < 4; ++j) acc[i][j] = (f32x4){0.f, 0.f, 0.f, 0.f};

    for (int k0 = 0; k0 < K; k0 += 64) {
        hard_sync();
        #pragma unroll
        for (int i = 0; i < 4; ++i) {
            int c = i * 256 + tid;
            int row = c >> 3;
            int colb = ((c & 7) << 4) ^ ((row & 7) << 4);
            gll16(A  + (size_t)(m0 + row) * K + k0 + (colb >> 1), Ald + i * 2048 + wid * 512);
            gll16(Bt + (size_t)(n0 + row) * K + k0 + (colb >> 1), Bld + i * 2048 + wid * 512);
        }
        hard_sync();

        #pragma unroll
        for (int ks = 0; ks < 2; ++ks) {
            bf16x8 af[4], bfr[4];
            #pragma unroll
            for (int mi = 0; mi < 4; ++mi) {
                int row = wr * 64 + mi * 16 + l15;
                af[mi] = *(const bf16x8*)((const char*)Ald + row * 128 +
                                          ((ks * 64 + g * 16) ^ ((row & 7) << 4)));
            }
            #pragma unroll
            for (int nj = 0; nj < 4; ++nj) {
                int row = wc * 64 + nj * 16 + l15;
                bfr[nj] = *(const bf16x8*)((const char*)Bld + row * 128 +
                                           ((ks * 64 + g * 16) ^ ((row & 7) << 4)));
            }
            #pragma unroll
            for (int mi = 0; mi < 4; ++mi)
                #pragma unroll
                for (int nj = 0; nj < 4; ++nj)
                    acc[mi][nj] = __builtin_amdgcn_mfma_f32_16x16x32_bf16(
                        af[mi], bfr[nj], acc[mi][nj], 0, 0, 0);
        }
    }

    if (EPI == 0) {
        #pragma unroll
        for (int nj = 0; nj < 4; ++nj) {
            int col = n0 + wc * 64 + nj * 16 + l15;
            float bv = bias[col];
            #pragma unroll
            for (int mi = 0; mi < 4; ++mi) {
                int rowb = m0 + wr * 64 + mi * 16 + g * 4;
                #pragma unroll
                for (int r = 0; r < 4; ++r)
                    Cout[(size_t)(rowb + r) * N + col] = acc[mi][nj][r] + bv;
            }
        }
    } else {
        #pragma unroll
        for (int nj = 0; nj < 4; ++nj) {
            int col = n0 + wc * 64 + nj * 16 + l15;   // 0..3071
            float bv = bias[col];
            int which = col >> 10;
            int c10 = col & 1023;
            int h = c10 >> 6, d = c10 & 63;
            #pragma unroll
            for (int mi = 0; mi < 4; ++mi) {
                #pragma unroll
                for (int r = 0; r < 4; ++r) {
                    int row = m0 + wr * 64 + mi * 16 + g * 4 + r;  // 0..4095
                    int bb = row >> 11, t = row & 2047;
                    unsigned short val = f2bf(acc[mi][nj][r] + bv);
                    if (which == 2)
                        vT_ws[((size_t)(bb * H_SZ + h) * HD + d) * T_SZ + t] = val;       // V^T
                    else
                        (which ? k_ws : q_ws)[((size_t)(bb * H_SZ + h) * T_SZ + t) * HD + d] = val;
                }
            }
        }
    }
}

// ---------------- causal flash attention, QBLK=128 / KVBLK=128 / att[2] pipeline ----
// 256 blocks (1/CU): xcd=n&7, j=(n>>3)&7, rk=n>>6. bh = xcd + 8*rk.
// Per iteration i: QK^T(i) ; PV(i-1) ; softmax(i) — the two MFMA clusters are
// independent and issue back-to-back; softmax VALU overlaps PV execution (T15).
// P carried as packed post-permlane fragments (pfA/pfB, static names, rule #20).
// V triple-buffered: PV(i-1) reads V(i-1) while prefetch writes V(i+1).
__global__ __launch_bounds__(512) void k_attn(const unsigned short* __restrict__ q_ws,
                                              const unsigned short* __restrict__ k_ws,
                                              const unsigned short* __restrict__ vT_ws,
                                              unsigned short* __restrict__ y_ws) {
    __shared__ __attribute__((aligned(16))) unsigned short Kbuf[2][8192];  // [128 keys][64 d]
    __shared__ __attribute__((aligned(16))) unsigned short Vbuf[3][8192];  // [64 d][128 t]
    const int tid = threadIdx.x;
    const int wid = tid >> 6, lane = tid & 63;
    const int g = lane >> 4, l15 = lane & 15;
    const int n = blockIdx.x;
    const int xcd = n & 7, j = (n >> 3) & 7, rk = n >> 6;
    const int bh = xcd + 8 * rk;
    const size_t kv_off = (size_t)bh * T_SZ * HD;
    const unsigned short* Kg = k_ws + kv_off;
    const unsigned short* Vg = vT_ws + (size_t)bh * HD * T_SZ;
    const int b = bh >> 4, h = bh & 15;
    const float SC = 0.125f * 1.44269504f;  // 1/sqrt(64) * log2(e)
    const int qloc = wid * 16 + l15;        // q row within the 128-row tile

    auto stageK = [&](int kv, int buf) {        // 128x64 bf16, swz (row&7)<<4
        #pragma unroll
        for (int i = 0; i < 2; ++i) {
            int c = i * 512 + tid;
            int row = c >> 3;
            int colb = ((c & 7) << 4) ^ ((row & 7) << 4);
            gll16(Kg + (size_t)(kv * 128 + row) * HD + (colb >> 1),
                  &Kbuf[buf][i * 4096 + wid * 512]);
        }
    };
    auto stageV = [&](int kv, int buf) {        // 64x128 bf16 (V^T), swz (row&15)<<4
        #pragma unroll
        for (int i = 0; i < 2; ++i) {
            int c = i * 512 + tid;
            int row = c >> 4;                               // d index
            int colb = ((c & 15) << 4) ^ ((row & 15) << 4); // t-offset bytes in 256B row
            gll16(Vg + (size_t)row * T_SZ + kv * 128 + (colb >> 1),
                  &Vbuf[buf][i * 4096 + wid * 512]);
        }
    };

    #pragma unroll 1
    for (int phase = 0; phase < 2; ++phase) {
        const int qt = phase ? j : (15 - j);    // 128-row q-tile index
        const int nkv = qt + 1;                 // KV steps (128 keys each)

        const int qrow = qt * 128 + wid * 16 + l15;
        bf16x8 aq[2];
        aq[0] = *(const bf16x8*)(q_ws + kv_off + (size_t)qrow * HD + g * 8);
        aq[1] = *(const bf16x8*)(q_ws + kv_off + (size_t)qrow * HD + 32 + g * 8);

        float m_run = -3e38f, l_part = 0.f;
        f32x4 acc[4];
        #pragma unroll
        for (int dt = 0; dt < 4; ++dt) acc[dt] = (f32x4){0.f, 0.f, 0.f, 0.f};
        u32x4 pfA[4], pfB[4];

        // QK^T(i): S^T = K @ Q^T, lane holds keys kt*16+4g+r for q=l15
        auto qk = [&](const char* Kb, f32x4 (&st)[8]) {
            __builtin_amdgcn_s_setprio(1);
            #pragma unroll
            for (int kt = 0; kt < 8; ++kt) {
                f32x4 sv = (f32x4){0.f, 0.f, 0.f, 0.f};
                #pragma unroll
                for (int ks = 0; ks < 2; ++ks) {
                    int row = kt * 16 + l15;
                    bf16x8 ak = *(const bf16x8*)(Kb + row * 128 +
                                                 ((ks * 64 + g * 16) ^ ((row & 7) << 4)));
                    sv = __builtin_amdgcn_mfma_f32_16x16x32_bf16(ak, aq[ks], sv, 0, 0, 0);
                }
                st[kt] = sv;
            }
            __builtin_amdgcn_s_setprio(0);
        };
        // PV of a previous tile from packed fragments
        auto pv = [&](const char* Vb, const u32x4 (&pf)[4]) {
            __builtin_amdgcn_s_setprio(1);
            #pragma unroll
            for (int ks = 0; ks < 4; ++ks) {
                bf16x8 ap = __builtin_bit_cast(bf16x8, pf[ks]);
                #pragma unroll
                for (int dt = 0; dt < 4; ++dt) {
                    int row = dt * 16 + l15;
                    bf16x8 bv = *(const bf16x8*)(Vb + row * 256 +
                                                 ((ks * 64 + g * 16) ^ ((row & 15) << 4)));
                    acc[dt] = __builtin_amdgcn_mfma_f32_16x16x32_bf16(ap, bv, acc[dt], 0, 0, 0);
                }
            }
            __builtin_amdgcn_s_setprio(0);
        };
        // softmax(i): masks, online max (defer-max T13), exp2, l partial, pack P
        auto softmax = [&](f32x4 (&st)[8], bool diag, u32x4 (&pf)[4]) {
            float t[32];
            #pragma unroll
            for (int kt = 0; kt < 8; ++kt)
                #pragma unroll
                for (int r = 0; r < 4; ++r) t[kt * 4 + r] = st[kt][r];
            if (diag) {
                #pragma unroll
                for (int kt = 0; kt < 8; ++kt)
                    #pragma unroll
                    for (int r = 0; r < 4; ++r)
                        if (kt * 16 + g * 4 + r > qloc) t[kt * 4 + r] = -3e38f;
            }
            float m16v[16];
            #pragma unroll
            for (int i2 = 0; i2 < 16; ++i2) m16v[i2] = fmaxf(t[i2], t[i2 + 16]);
            float m8v[8];
            #pragma unroll
            for (int i2 = 0; i2 < 8; ++i2) m8v[i2] = fmaxf(m16v[i2], m16v[i2 + 8]);
            float m4v[4];
            #pragma unroll
            for (int i2 = 0; i2 < 4; ++i2) m4v[i2] = fmaxf(m8v[i2], m8v[i2 + 4]);
            float mx = fmaxf(fmaxf(m4v[0], m4v[1]), fmaxf(m4v[2], m4v[3]));
            mx = fmaxf(mx, __shfl_xor(mx, 16, 64));
            mx = fmaxf(mx, __shfl_xor(mx, 32, 64));
            float mt = mx * SC;
            if (!__all(mt - m_run <= 8.0f)) {
                float mnew = fmaxf(m_run, mt);
                float alpha = exp2f(m_run - mnew);   // uniform within 4-lane q-group
                m_run = mnew;
                l_part *= alpha;
                float ao[4];
                #pragma unroll
                for (int r = 0; r < 4; ++r) {
                    int ai = __builtin_amdgcn_ds_bpermute((g * 4 + r) * 4,
                                                          __builtin_bit_cast(int, alpha));
                    ao[r] = __builtin_bit_cast(float, ai);
                }
                #pragma unroll
                for (int dt = 0; dt < 4; ++dt)
                    #pragma unroll
                    for (int r = 0; r < 4; ++r) acc[dt][r] *= ao[r];
            }
            float p[32];
            #pragma unroll
            for (int i2 = 0; i2 < 32; ++i2) p[i2] = exp2f(fmaf(t[i2], SC, -m_run));
            float s16v[16];
            #pragma unroll
            for (int i2 = 0; i2 < 16; ++i2) s16v[i2] = p[i2] + p[i2 + 16];
            float s8v[8];
            #pragma unroll
            for (int i2 = 0; i2 < 8; ++i2) s8v[i2] = s16v[i2] + s16v[i2 + 8];
            float s4v[4];
            #pragma unroll
            for (int i2 = 0; i2 < 4; ++i2) s4v[i2] = s8v[i2] + s8v[i2 + 4];
            l_part += (s4v[0] + s4v[1]) + (s4v[2] + s4v[3]);
            #pragma unroll
            for (int ks = 0; ks < 4; ++ks) {
                unsigned int x0, y0, x1, y1;
                asm("v_cvt_pk_bf16_f32 %0, %1, %2" : "=v"(x0) : "v"(p[8 * ks + 0]), "v"(p[8 * ks + 1]));
                asm("v_cvt_pk_bf16_f32 %0, %1, %2" : "=v"(x1) : "v"(p[8 * ks + 2]), "v"(p[8 * ks + 3]));
                asm("v_cvt_pk_bf16_f32 %0, %1, %2" : "=v"(y0) : "v"(p[8 * ks + 4]), "v"(p[8 * ks + 5]));
                asm("v_cvt_pk_bf16_f32 %0, %1, %2" : "=v"(y1) : "v"(p[8 * ks + 6]), "v"(p[8 * ks + 7]));
                asm("v_permlane32_swap_b32 %0, %1" : "+v"(x0), "+v"(y0));
                asm("v_permlane16_swap_b32 %0, %1" : "+v"(x0), "+v"(y0));
                asm("v_permlane32_swap_b32 %0, %1" : "+v"(x1), "+v"(y1));
                asm("v_permlane16_swap_b32 %0, %1" : "+v"(x1), "+v"(y1));
                pf[ks] = (u32x4){x0, x1, y0, y1};
            }
        };

        hard_sync();              // all waves done reading buffers (prev phase)
        stageK(0, 0); stageV(0, 0);

        // peel i = 0: produce pfA, nothing to consume
        hard_sync();
        if (1 < nkv) { stageK(1, 1); stageV(1, 1); }
        {
            f32x4 st[8];
            qk((const char*)Kbuf[0], st);
            softmax(st, nkv == 1, pfA);
        }
        bool lastA = true;
        for (int i = 1; i < nkv; ) {
            // produce B, consume A (tile i-1)
            hard_sync();
            if (i + 1 < nkv) { stageK(i + 1, (i + 1) & 1); stageV(i + 1, (i + 1) % 3); }
            {
                f32x4 st[8];
                qk((const char*)Kbuf[i & 1], st);
                pv((const char*)Vbuf[(i - 1) % 3], pfA);
                softmax(st, i == nkv - 1, pfB);
            }
            ++i; lastA = false; if (i == nkv) break;
            // produce A, consume B (tile i-1)
            hard_sync();
            if (i + 1 < nkv) { stageK(i + 1, (i + 1) & 1); stageV(i + 1, (i + 1) % 3); }
            {
                f32x4 st[8];
                qk((const char*)Kbuf[i & 1], st);
                pv((const char*)Vbuf[(i - 1) % 3], pfB);
                softmax(st, i == nkv - 1, pfA);
            }
            ++i; lastA = true; if (i == nkv) break;
        }
        // tail: PV of the last tile (its V buffer is untouched after its stage)
        if (lastA) pv((const char*)Vbuf[(nkv - 1) % 3], pfA);
        else       pv((const char*)Vbuf[(nkv - 1) % 3], pfB);

        // epilogue: reduce l across the 4-lane q-group, gather for q=4g+r, store
        float lsum = l_part;
        lsum += __shfl_xor(lsum, 16, 64);
        lsum += __shfl_xor(lsum, 32, 64);
        float lo[4];
        #pragma unroll
        for (int r = 0; r < 4; ++r) {
            int li = __builtin_amdgcn_ds_bpermute((g * 4 + r) * 4,
                                                  __builtin_bit_cast(int, lsum));
            lo[r] = __builtin_bit_cast(float, li);
        }
        #pragma unroll
        for (int r = 0; r < 4; ++r) {
            int tq = qt * 128 + wid * 16 + g * 4 + r;
            float inv = 1.0f / lo[r];
            #pragma unroll
            for (int dt = 0; dt < 4; ++dt)
                y_ws[(size_t)(b * T_SZ + tq) * C_SZ + h * 64 + dt * 16 + l15] =
                    f2bf(acc[dt][r] * inv);
        }
    }
}

// ---------------- launcher ----------------
extern "C" void kernel_launch(void* const* d_in, const int* in_sizes, int n_in,
                              void* d_out, int out_size, void* d_ws, size_t ws_size,
                              hipStream_t stream) {
    const float* x      = (const float*)d_in[0];
    const float* w_attn = (const float*)d_in[1];
    const float* b_attn = (const float*)d_in[2];
    const float* w_proj = (const float*)d_in[3];
    const float* b_proj = (const float*)d_in[4];
    float* out = (float*)d_out;

    char* ws = (char*)d_ws;
    unsigned short* q_ws  = (unsigned short*)(ws + 0);         // 8 MB [BH][T][HD]
    unsigned short* k_ws  = (unsigned short*)(ws + 8388608);   // 8 MB [BH][T][HD]
    unsigned short* vT_ws = (unsigned short*)(ws + 16777216);  // 8 MB [BH][HD][T]
    unsigned short* wtp   = (unsigned short*)(ws + 25165824);  // 2 MB [C][C]
    unsigned short* xb    = (unsigned short*)(ws + 27262976);  // 8 MB x as bf16
    unsigned short* y_ws  = (unsigned short*)(ws + 27262976);  // aliases xb (xb dead by then)
    unsigned short* wta   = (unsigned short*)(ws + 35651584);  // 6 MB [3C][C]

    // 1) fused prep: x->bf16 + both weight transposes
    k_prep<<<dim3(6144), 256, 0, stream>>>(x, w_attn, w_proj, xb, wta, wtp);

    // 2) QKV GEMM -> Q/K row-major + V^T   (grid 768, %8==0)
    k_gemm<1><<<dim3((N_QKV / 128) * (M_SZ / 128)), 256, 0, stream>>>(
        xb, wta, b_attn, nullptr, q_ws, k_ws, vT_ws, M_SZ, N_QKV, C_SZ, N_QKV / 128);

    // 3) causal flash attention -> y bf16 [B][T][C]  (256 blocks x 512 thr)
    k_attn<<<dim3(256), 512, 0, stream>>>(q_ws, k_ws, vT_ws, y_ws);

    // 4) proj GEMM: y @ w_proj + b_proj -> f32 out  (grid 256, %8==0)
    k_gemm<0><<<dim3((C_SZ / 128) * (M_SZ / 128)), 256, 0, stream>>>(
        y_ws, wtp, b_proj, out, nullptr, nullptr, nullptr, M_SZ, C_SZ, C_SZ, C_SZ / 128);
}